// Round 7
// baseline (1200.307 us; speedup 1.0000x reference)
//
#include <hip/hip_runtime.h>

// Problem constants (B=4, C=64, H=W=192)
#define HH 192
#define WID 192
#define HW (HH*WID)          // 36864
#define CB 64
#define BB 4
#define NPOS (BB*HW)         // 147456

typedef __attribute__((ext_vector_type(8))) _Float16 half8v;
typedef __attribute__((ext_vector_type(4))) _Float16 half4v;
typedef __attribute__((ext_vector_type(4))) float f32x4;
typedef __attribute__((ext_vector_type(16))) float f32x16;

static __device__ inline half8v splat8(_Float16 x) {
    half8v v = {x, x, x, x, x, x, x, x};
    return v;
}

// x tensors: CHANNEL-PLANE fp16 layout x[b][plane=c>>3][hw][8ch] (16B/pos/plane).
// Offsets: TAP-MAJOR float2 planes off[k][global_pos][2] (NPOS float2 per plane).

// ---------------------------------------------------------------------------
// K1: LayerNorm over C + 1x1 conv C->2C; outputs x1/x2 in plane-fp16 layout.
// ---------------------------------------------------------------------------
__global__ __launch_bounds__(256) void k_ln_conv_in(
    const float* __restrict__ x, const float* __restrict__ g, const float* __restrict__ be,
    const float* __restrict__ w_in, const float* __restrict__ b_in,
    _Float16* __restrict__ x1, _Float16* __restrict__ x2)
{
    int p  = blockIdx.x * 256 + threadIdx.x;     // [0, NPOS)
    int b  = p / HW;
    int hw = p % HW;
    const float* xp = x + (size_t)b * CB * HW + hw;

    float v[64];
    float sum = 0.f, sumsq = 0.f;
#pragma unroll
    for (int c = 0; c < 64; c++) {
        float t = xp[c * HW];
        v[c] = t; sum += t; sumsq += t * t;
    }
    float mu  = sum * (1.f / 64.f);
    float var = sumsq * (1.f / 64.f) - mu * mu;
    float inv = rsqrtf(var + 1e-5f);
#pragma unroll
    for (int c = 0; c < 64; c++) v[c] = (v[c] - mu) * inv * g[c] + be[c];

    _Float16* o1 = x1 + (size_t)b * HW * 64 + (size_t)hw * 8;
    _Float16* o2 = x2 + (size_t)b * HW * 64 + (size_t)hw * 8;
    for (int pl = 0; pl < 8; pl++) {            // pl = channel plane (8 ch)
        half8v r1, r2;
#pragma unroll
        for (int j = 0; j < 8; j++) {
            int o = pl * 8 + j;
            float a1 = b_in[o];
            float a2 = b_in[o + 64];
#pragma unroll
            for (int c = 0; c < 64; c++) {
                a1 += v[c] * w_in[o * 64 + c];
                a2 += v[c] * w_in[(o + 64) * 64 + c];
            }
            r1[j] = (_Float16)a1;
            r2[j] = (_Float16)a2;
        }
        *(half8v*)&o1[(size_t)pl * HW * 8] = r1;
        *(half8v*)&o2[(size_t)pl * HW * 8] = r2;
    }
}

// ---------------------------------------------------------------------------
// Weight prep: w[o][c][ki][kj] fp32 (OIHW) -> wt[k][o][c] fp16, o padded to OP.
// ---------------------------------------------------------------------------
template<int KK, int CO, int OP>
__global__ void k_wth(const float* __restrict__ w, _Float16* __restrict__ wt)
{
    int idx = blockIdx.x * 256 + threadIdx.x;
    constexpr int TOT = KK * OP * 64;
    if (idx >= TOT) return;
    int k = idx / (OP * 64);
    int r = idx % (OP * 64);
    int o = r / 64;
    int c = r % 64;
    float v = (o < CO) ? w[((size_t)o * 64 + c) * KK + k] : 0.f;
    wt[idx] = (_Float16)v;
}

// ---------------------------------------------------------------------------
// k_sconv v6 (UNCHANGED from round 6, best measured deform: 255us @ K=7):
// LDS-staged deform conv with 32x32x16 MFMA. 16x8-position block, 256 thr,
// grid 1152, staged (16+2H)x(8+2H) px * 128B -> 48/38.5/30 KB LDS.
// Wave = 32 positions (4 rows x 8 cols) x 64 out-ch; 2 lanes/position.
// Swizzle: 16B slot = pl ^ (pix & 7) at write and read.
// Per-lane global fallback when a corner exits the halo (|off|>=1).
// ---------------------------------------------------------------------------
template<int K, int PAD, int HALO>
__global__ __launch_bounds__(256) void k_sconv(
    const _Float16* __restrict__ xin, const float* __restrict__ offp,
    const _Float16* __restrict__ wtb, const float* __restrict__ bias,
    _Float16* __restrict__ outp)
{
    constexpr int KK = K * K;
    constexpr int RB = 16 + 2 * HALO;     // staged rows
    constexpr int WB = 8  + 2 * HALO;     // staged cols

    __shared__ half8v sm[RB * WB * 8];    // 16B slot per (pixel, plane)

    int bi  = blockIdx.x;
    int b   = bi / 288;                   // 288 = 12 row-tiles * 24 col-tiles
    int tt  = bi % 288;
    int by0 = (tt / 24) * 16;
    int bx0 = (tt % 24) * 8;
    int ry0 = by0 - HALO;
    int rx0 = bx0 - HALO;

    const _Float16* xb  = xin + (size_t)b * HW * 64;

    // ---- stage tile + halo (edge-clamped rows/cols) ----
    constexpr int CH = RB * WB * 8;       // 16B chunks
    for (int i = threadIdx.x; i < CH; i += 256) {
        int cc = i % WB;
        int rp = i / WB;
        int pl = rp & 7;
        int r  = rp >> 3;
        int yr = min(max(ry0 + r,  0), HH - 1);
        int xc = min(max(rx0 + cc, 0), WID - 1);
        half8v ch = *(const half8v*)(xb + ((size_t)pl * HW + (size_t)(yr * WID + xc)) * 8);
        int pix = r * WB + cc;
        sm[pix * 8 + (pl ^ (pix & 7))] = ch;
    }
    __syncthreads();

    int t    = threadIdx.x;
    int lane = t & 63;
    int wave = t >> 6;                    // 0..3 -> rows wave*4..wave*4+3
    int l31  = lane & 31;                 // position index within wave tile
    int h    = lane >> 5;                 // K-half (channel chunk parity)
    int prow = l31 >> 3;                  // 0..3
    int pcol = l31 & 7;                   // 0..7

    int yt = by0 + wave * 4 + prow;
    int xt = bx0 + pcol;
    int gp = b * HW + yt * WID + xt;

    const half8v* wbase = (const half8v*)wtb;

    f32x16 acc0 = {0.f,0.f,0.f,0.f,0.f,0.f,0.f,0.f,0.f,0.f,0.f,0.f,0.f,0.f,0.f,0.f};
    f32x16 acc1 = {0.f,0.f,0.f,0.f,0.f,0.f,0.f,0.f,0.f,0.f,0.f,0.f,0.f,0.f,0.f,0.f};

    const float2* offj = (const float2*)offp + gp;
    float2 offc = offj[0];

    int ki = 0, kj = 0;
    for (int k = 0; k < KK; k++) {
        // prefetch next tap's offset (one tap of cover, v1-proven)
        float2 offn = offj[(size_t)(k + 1) * NPOS];

        // A-frags: W[o][c], o = t*32 + l31, chunk = 2m + h
        const half8v* wp = wbase + (size_t)k * 64 * 8;   // OP = 64
        half8v a0[4], a1[4];
#pragma unroll
        for (int m = 0; m < 4; m++) {
            a0[m] = wp[(size_t)l31 * 8 + m * 2 + h];
            a1[m] = wp[(size_t)(32 + l31) * 8 + m * 2 + h];
        }

        // per-lane sample coordinates (ONE position per lane-pair)
        float py = (float)(yt + ki - PAD) + offc.x;
        float px = (float)(xt + kj - PAD) + offc.y;
        float fy = floorf(py), fx = floorf(px);
        float wy = py - fy, wx = px - fx;
        int iy0 = (int)fy, ix0 = (int)fx;
        int iy1 = iy0 + 1, ix1 = ix0 + 1;
        float m00 = (iy0 >= 0 && iy0 < HH && ix0 >= 0 && ix0 < WID) ? 1.f : 0.f;
        float m01 = (iy0 >= 0 && iy0 < HH && ix1 >= 0 && ix1 < WID) ? 1.f : 0.f;
        float m10 = (iy1 >= 0 && iy1 < HH && ix0 >= 0 && ix0 < WID) ? 1.f : 0.f;
        float m11 = (iy1 >= 0 && iy1 < HH && ix1 >= 0 && ix1 < WID) ? 1.f : 0.f;
        half8v w00v = splat8((_Float16)((1.f - wy) * (1.f - wx) * m00));
        half8v w01v = splat8((_Float16)((1.f - wy) * wx * m01));
        half8v w10v = splat8((_Float16)(wy * (1.f - wx) * m10));
        half8v w11v = splat8((_Float16)(wy * wx * m11));

        bool fast = (iy0 >= ry0) && (iy1 <= ry0 + RB - 1) &&
                    (ix0 >= rx0) && (ix1 <= rx0 + WB - 1);

        if (__builtin_expect(fast, 1)) {
            int p00 = (iy0 - ry0) * WB + (ix0 - rx0);
            int p01 = p00 + 1, p10 = p00 + WB, p11 = p00 + WB + 1;
            int s00 = p00 & 7, s01 = p01 & 7, s10 = p10 & 7, s11 = p11 & 7;
#pragma unroll
            for (int m = 0; m < 4; m++) {
                int cs = m * 2 + h;
                half8v c00 = sm[p00 * 8 + (cs ^ s00)];
                half8v c01 = sm[p01 * 8 + (cs ^ s01)];
                half8v c10 = sm[p10 * 8 + (cs ^ s10)];
                half8v c11 = sm[p11 * 8 + (cs ^ s11)];
                half8v bf = c00 * w00v + c01 * w01v + c10 * w10v + c11 * w11v;
                acc0 = __builtin_amdgcn_mfma_f32_32x32x16_f16(a0[m], bf, acc0, 0, 0, 0);
                acc1 = __builtin_amdgcn_mfma_f32_32x32x16_f16(a1[m], bf, acc1, 0, 0, 0);
            }
        } else {
            int cy0 = min(max(iy0, 0), HH - 1), cy1 = min(max(iy1, 0), HH - 1);
            int cx0 = min(max(ix0, 0), WID - 1), cx1 = min(max(ix1, 0), WID - 1);
            size_t i00 = (size_t)(cy0 * WID + cx0) * 8, i01 = (size_t)(cy0 * WID + cx1) * 8;
            size_t i10 = (size_t)(cy1 * WID + cx0) * 8, i11 = (size_t)(cy1 * WID + cx1) * 8;
#pragma unroll
            for (int m = 0; m < 4; m++) {
                const _Float16* xq = xb + (size_t)(m * 2 + h) * HW * 8;
                half8v c00 = *(const half8v*)(xq + i00);
                half8v c01 = *(const half8v*)(xq + i01);
                half8v c10 = *(const half8v*)(xq + i10);
                half8v c11 = *(const half8v*)(xq + i11);
                half8v bf = c00 * w00v + c01 * w01v + c10 * w10v + c11 * w11v;
                acc0 = __builtin_amdgcn_mfma_f32_32x32x16_f16(a0[m], bf, acc0, 0, 0, 0);
                acc1 = __builtin_amdgcn_mfma_f32_32x32x16_f16(a1[m], bf, acc1, 0, 0, 0);
            }
        }

        offc = offn;
        kj++;
        if (kj == K) { kj = 0; ki++; }
    }

    // ---- epilogue: D: pos = l31, o = t*32 + (reg&3) + 8*(reg>>2) + 4*h ----
    int hwp = yt * WID + xt;
    _Float16* ob = outp + (size_t)b * HW * 64 + (size_t)hwp * 8 + 4 * h;
#pragma unroll
    for (int g = 0; g < 4; g++) {
        // tile 0: o = g*8 + 4h + i, plane = g
        float4 bb0 = *(const float4*)&bias[g * 8 + 4 * h];
        half4v r0;
        r0[0] = (_Float16)(acc0[g * 4 + 0] + bb0.x);
        r0[1] = (_Float16)(acc0[g * 4 + 1] + bb0.y);
        r0[2] = (_Float16)(acc0[g * 4 + 2] + bb0.z);
        r0[3] = (_Float16)(acc0[g * 4 + 3] + bb0.w);
        *(half4v*)&ob[(size_t)g * HW * 8] = r0;
        // tile 1: o = 32 + g*8 + 4h + i, plane = 4 + g
        float4 bb1 = *(const float4*)&bias[32 + g * 8 + 4 * h];
        half4v r1;
        r1[0] = (_Float16)(acc1[g * 4 + 0] + bb1.x);
        r1[1] = (_Float16)(acc1[g * 4 + 1] + bb1.y);
        r1[2] = (_Float16)(acc1[g * 4 + 2] + bb1.z);
        r1[3] = (_Float16)(acc1[g * 4 + 3] + bb1.w);
        *(half4v*)&ob[(size_t)(4 + g) * HW * 8] = r1;
    }
}

// ---------------------------------------------------------------------------
// k_soconv (NEW): LDS-staged REGULAR conv for the offset branches, 32x32x16
// MFMA, same 16x8-position block geometry as k_sconv. Differences vs deform:
//  - zero-fill staging (conv semantics) instead of edge-clamp; window reads
//    always hit the staged region (HALO = PAD), no fallback, no bilinear.
//  - per tap: ONE pixel per position -> 4 ds_read_b128/lane (4 K-chunks),
//    then NTILE x 4 MFMA -> MFMA-dominated.
//  - deterministic (jitter-free) read pattern: slot = (2m+h) ^ (pix&7) is
//    uniform 8 lanes/slot -> minimal bank conflicts.
//  - epilogue: tap-major float2 offset planes off[t0][pos][2], pair-guarded
//    by t0 < KTAP (= CO/2), which also guards bias reads (o+1 <= CO-1).
// D-layout: o = tile*32 + (reg&3) + 8*(reg>>2) + 4h (even bases -> clean
// float2 pairs).
// ---------------------------------------------------------------------------
template<int K, int PAD, int NTILE, int CO>
__global__ __launch_bounds__(256) void k_soconv(
    const _Float16* __restrict__ xin,
    const _Float16* __restrict__ wtb, const float* __restrict__ bias,
    float* __restrict__ outf)
{
    constexpr int KK = K * K;
    constexpr int KTAP = CO / 2;
    constexpr int HALO = PAD;
    constexpr int RB = 16 + 2 * HALO;
    constexpr int WB = 8  + 2 * HALO;
    constexpr int OP = NTILE * 32;

    __shared__ half8v sm[RB * WB * 8];

    int bi  = blockIdx.x;
    int b   = bi / 288;
    int tt  = bi % 288;
    int by0 = (tt / 24) * 16;
    int bx0 = (tt % 24) * 8;
    int ry0 = by0 - HALO;
    int rx0 = bx0 - HALO;

    const _Float16* xb = xin + (size_t)b * HW * 64;

    // ---- stage tile + halo, ZERO-FILL outside the image ----
    constexpr int CH = RB * WB * 8;
    for (int i = threadIdx.x; i < CH; i += 256) {
        int cc = i % WB;
        int rp = i / WB;
        int pl = rp & 7;
        int r  = rp >> 3;
        int yr = ry0 + r;
        int xc = rx0 + cc;
        bool ok = (yr >= 0 && yr < HH && xc >= 0 && xc < WID);
        half8v ch = ok ? *(const half8v*)(xb + ((size_t)pl * HW + (size_t)(yr * WID + xc)) * 8)
                       : splat8((_Float16)0.f);
        int pix = r * WB + cc;
        sm[pix * 8 + (pl ^ (pix & 7))] = ch;
    }
    __syncthreads();

    int lane = threadIdx.x & 63;
    int wave = threadIdx.x >> 6;          // 0..3
    int l31  = lane & 31;
    int h    = lane >> 5;
    int prow = l31 >> 3;
    int pcol = l31 & 7;

    int yt = by0 + wave * 4 + prow;
    int xt = bx0 + pcol;
    int gp = b * HW + yt * WID + xt;

    const half8v* wbase = (const half8v*)wtb;

    f32x16 acc[NTILE];
#pragma unroll
    for (int tI = 0; tI < NTILE; tI++)
#pragma unroll
        for (int r = 0; r < 16; r++) acc[tI][r] = 0.f;

    int ki = 0, kj = 0;
    for (int k = 0; k < KK; k++) {
        const half8v* wp = wbase + (size_t)k * OP * 8;

        // window pixel for this tap: always inside the staged region
        int rr  = (yt + ki - PAD) - ry0;     // in [0, RB)
        int ccx = (xt + kj - PAD) - rx0;     // in [0, WB)
        int pix = rr * WB + ccx;
        int s   = pix & 7;

#pragma unroll
        for (int m = 0; m < 4; m++) {
            int cs = m * 2 + h;
            half8v bf = sm[pix * 8 + (cs ^ s)];
#pragma unroll
            for (int tI = 0; tI < NTILE; tI++) {
                half8v a = wp[(size_t)(tI * 32 + l31) * 8 + cs];
                acc[tI] = __builtin_amdgcn_mfma_f32_32x32x16_f16(a, bf, acc[tI], 0, 0, 0);
            }
        }

        kj++;
        if (kj == K) { kj = 0; ki++; }
    }

    // ---- epilogue: tap-major float2 planes, o = tile*32 + i + 8g + 4h ----
#pragma unroll
    for (int tI = 0; tI < NTILE; tI++) {
#pragma unroll
        for (int g = 0; g < 4; g++) {
            int base = tI * 32 + 8 * g + 4 * h;
#pragma unroll
            for (int pr = 0; pr < 2; pr++) {
                int o  = base + 2 * pr;
                int t0 = o >> 1;
                if (t0 < KTAP) {
                    float2 r;
                    r.x = acc[tI][g * 4 + 2 * pr]     + bias[o];
                    r.y = acc[tI][g * 4 + 2 * pr + 1] + bias[o + 1];
                    *(float2*)&outf[((size_t)t0 * NPOS + gp) * 2] = r;
                }
            }
        }
    }
}

// ---------------------------------------------------------------------------
// K4: h = x1_final + x2 (plane fp16); out = h @ w_out^T + b_out + x (NCHW fp32)
// ---------------------------------------------------------------------------
__global__ __launch_bounds__(256) void k_merge_out(
    const _Float16* __restrict__ x1f, const _Float16* __restrict__ x2,
    const float* __restrict__ xin, const float* __restrict__ w_out,
    const float* __restrict__ b_out, float* __restrict__ out)
{
    int p  = blockIdx.x * 256 + threadIdx.x;
    int b  = p / HW;
    int hw = p % HW;

    const _Float16* a1 = x1f + (size_t)b * HW * 64 + (size_t)hw * 8;
    const _Float16* a2 = x2  + (size_t)b * HW * 64 + (size_t)hw * 8;
    float v[64];
#pragma unroll
    for (int pl = 0; pl < 8; pl++) {
        half8v u1 = *(const half8v*)&a1[(size_t)pl * HW * 8];
        half8v u2 = *(const half8v*)&a2[(size_t)pl * HW * 8];
#pragma unroll
        for (int j = 0; j < 8; j++)
            v[pl * 8 + j] = (float)u1[j] + (float)u2[j];
    }

    size_t base = (size_t)b * CB * HW + hw;
    for (int o = 0; o < 64; o++) {
        float a = b_out[o] + xin[base + (size_t)o * HW];
#pragma unroll
        for (int c = 0; c < 64; c++) a += v[c] * w_out[o * 64 + c];
        out[base + (size_t)o * HW] = a;
    }
}

// ---------------------------------------------------------------------------
// Launch. Workspace: x1a/x1b/x2 plane fp16 (18.9 MB each), off tap-major
// float2 planes (50 planes * NPOS * 8B = 59 MB), fp16 weights (~1.4 MB,
// wto1 now padded to OP=128 for the 32x32 MFMA tiles).
// ---------------------------------------------------------------------------
extern "C" void kernel_launch(void* const* d_in, const int* in_sizes, int n_in,
                              void* d_out, int out_size, void* d_ws, size_t ws_size,
                              hipStream_t stream)
{
    const float* x     = (const float*)d_in[0];
    const float* ln_w  = (const float*)d_in[1];
    const float* ln_b  = (const float*)d_in[2];
    const float* w_in  = (const float*)d_in[3];
    const float* b_in  = (const float*)d_in[4];
    const float* w_out = (const float*)d_in[5];
    const float* b_out = (const float*)d_in[6];
    const float* dw1   = (const float*)d_in[7];
    const float* db1   = (const float*)d_in[8];
    const float* dw2   = (const float*)d_in[9];
    const float* db2   = (const float*)d_in[10];
    const float* dw3   = (const float*)d_in[11];
    const float* db3   = (const float*)d_in[12];
    const float* ow1   = (const float*)d_in[13];
    const float* ob1   = (const float*)d_in[14];
    const float* ow2   = (const float*)d_in[15];
    const float* ob2   = (const float*)d_in[16];
    const float* ow3   = (const float*)d_in[17];
    const float* ob3   = (const float*)d_in[18];

    _Float16* x1a = (_Float16*)d_ws;
    _Float16* x1b = x1a + (size_t)NPOS * 64;
    _Float16* x2  = x1b + (size_t)NPOS * 64;
    float* off = (float*)(x2 + (size_t)NPOS * 64);
    _Float16* wtd1 = (_Float16*)(off + (size_t)NPOS * 100);
    _Float16* wtd2 = wtd1 + 49 * 64 * 64;
    _Float16* wtd3 = wtd2 + 25 * 64 * 64;
    _Float16* wto1 = wtd3 +  9 * 64 * 64;
    _Float16* wto2 = wto1 + 25 * 128 * 64;   // OP=128 now
    _Float16* wto3 = wto2 + 25 * 64 * 64;

    // weight prep (fp16, [tap][o][c]); offset-conv OP padded to 32-multiples
    k_wth<49, 64,  64><<<784, 256, 0, stream>>>(dw1, wtd1);
    k_wth<25, 64,  64><<<400, 256, 0, stream>>>(dw2, wtd2);
    k_wth< 9, 64,  64><<<144, 256, 0, stream>>>(dw3, wtd3);
    k_wth<25, 98, 128><<<800, 256, 0, stream>>>(ow1, wto1);
    k_wth<25, 50,  64><<<400, 256, 0, stream>>>(ow2, wto2);
    k_wth< 9, 18,  32><<< 72, 256, 0, stream>>>(ow3, wto3);

    k_ln_conv_in<<<NPOS / 256, 256, 0, stream>>>(x, ln_w, ln_b, w_in, b_in, x1a, x2);

    // offset convs: LDS-staged k_soconv (zero-fill staging, 32x32 MFMA)
    // deform convs: LDS-staged k_sconv v6 (unchanged, best measured)
    // stage 1
    k_soconv<5, 2, 4, 98><<<1152, 256, 0, stream>>>(x1a, wto1, ob1, off);
    k_sconv<7, 3, 4><<<1152, 256, 0, stream>>>(x1a, off, wtd1, db1, x1b);
    // stage 2
    k_soconv<5, 2, 2, 50><<<1152, 256, 0, stream>>>(x1b, wto2, ob2, off);
    k_sconv<5, 2, 3><<<1152, 256, 0, stream>>>(x1b, off, wtd2, db2, x1a);
    // stage 3
    k_soconv<3, 1, 1, 18><<<1152, 256, 0, stream>>>(x1a, wto3, ob3, off);
    k_sconv<3, 1, 2><<<1152, 256, 0, stream>>>(x1a, off, wtd3, db3, x1b);

    k_merge_out<<<NPOS / 256, 256, 0, stream>>>(x1b, x2, x, w_out, b_out, (float*)d_out);
}

// Round 8
// 744.899 us; speedup vs baseline: 1.6114x; 1.6114x over previous
//
#include <hip/hip_runtime.h>

// Problem constants (B=4, C=64, H=W=192)
#define HH 192
#define WID 192
#define HW (HH*WID)          // 36864
#define CB 64
#define BB 4
#define NPOS (BB*HW)         // 147456

typedef __attribute__((ext_vector_type(8))) _Float16 half8v;
typedef __attribute__((ext_vector_type(4))) _Float16 half4v;
typedef __attribute__((ext_vector_type(4))) float f32x4;
typedef __attribute__((ext_vector_type(16))) float f32x16;

static __device__ inline half8v splat8(_Float16 x) {
    half8v v = {x, x, x, x, x, x, x, x};
    return v;
}

// x tensors: CHANNEL-PLANE fp16 layout x[b][plane=c>>3][hw][8ch] (16B/pos/plane).
// Offsets: TAP-MAJOR float2 planes off[k][global_pos][2] (NPOS float2 per plane).
// Weights (NEW round 8): FRAGMENT-MAJOR fp16 wt[k][cs][o][8ch], cs = channel
// chunk (8 ch). A-frag load = wbase[(k*8+cs)*OP + o_idx] -> 32 consecutive
// lanes read 512B contiguous (4 cache lines/instr vs 32 with the old
// [k][o][c] layout -- the L2-line-traffic bottleneck measured in round 7).

// ---------------------------------------------------------------------------
// K1: LayerNorm over C + 1x1 conv C->2C; outputs x1/x2 in plane-fp16 layout.
// ---------------------------------------------------------------------------
__global__ __launch_bounds__(256) void k_ln_conv_in(
    const float* __restrict__ x, const float* __restrict__ g, const float* __restrict__ be,
    const float* __restrict__ w_in, const float* __restrict__ b_in,
    _Float16* __restrict__ x1, _Float16* __restrict__ x2)
{
    int p  = blockIdx.x * 256 + threadIdx.x;     // [0, NPOS)
    int b  = p / HW;
    int hw = p % HW;
    const float* xp = x + (size_t)b * CB * HW + hw;

    float v[64];
    float sum = 0.f, sumsq = 0.f;
#pragma unroll
    for (int c = 0; c < 64; c++) {
        float t = xp[c * HW];
        v[c] = t; sum += t; sumsq += t * t;
    }
    float mu  = sum * (1.f / 64.f);
    float var = sumsq * (1.f / 64.f) - mu * mu;
    float inv = rsqrtf(var + 1e-5f);
#pragma unroll
    for (int c = 0; c < 64; c++) v[c] = (v[c] - mu) * inv * g[c] + be[c];

    _Float16* o1 = x1 + (size_t)b * HW * 64 + (size_t)hw * 8;
    _Float16* o2 = x2 + (size_t)b * HW * 64 + (size_t)hw * 8;
    for (int pl = 0; pl < 8; pl++) {            // pl = channel plane (8 ch)
        half8v r1, r2;
#pragma unroll
        for (int j = 0; j < 8; j++) {
            int o = pl * 8 + j;
            float a1 = b_in[o];
            float a2 = b_in[o + 64];
#pragma unroll
            for (int c = 0; c < 64; c++) {
                a1 += v[c] * w_in[o * 64 + c];
                a2 += v[c] * w_in[(o + 64) * 64 + c];
            }
            r1[j] = (_Float16)a1;
            r2[j] = (_Float16)a2;
        }
        *(half8v*)&o1[(size_t)pl * HW * 8] = r1;
        *(half8v*)&o2[(size_t)pl * HW * 8] = r2;
    }
}

// ---------------------------------------------------------------------------
// Weight prep: w[o][c][ki][kj] fp32 (OIHW) -> wt[k][cs][o][j] fp16
// (fragment-major; o padded to OP; c = cs*8 + j).
// ---------------------------------------------------------------------------
template<int KK, int CO, int OP>
__global__ void k_wth(const float* __restrict__ w, _Float16* __restrict__ wt)
{
    int idx = blockIdx.x * 256 + threadIdx.x;
    constexpr int TOT = KK * OP * 64;
    if (idx >= TOT) return;
    int k  = idx / (OP * 64);
    int r  = idx % (OP * 64);
    int cs = r / (OP * 8);
    int r2 = r % (OP * 8);
    int o  = r2 / 8;
    int j  = r2 % 8;
    int c  = cs * 8 + j;
    float v = (o < CO) ? w[((size_t)o * 64 + c) * KK + k] : 0.f;
    wt[idx] = (_Float16)v;
}

// ---------------------------------------------------------------------------
// k_sconv v7: = v6 (best measured deform structure) with fragment-major
// coalesced weight loads. 16x8-position block, 256 thr, grid 1152, staged
// (16+2H)x(8+2H) px * 128B -> 48/38.5/30 KB LDS. Wave = 32 positions
// (4 rows x 8 cols) x 64 out-ch via mfma_f32_32x32x16_f16; 2 lanes/position.
// Swizzle: 16B slot = pl ^ (pix & 7) at write and read.
// Per-lane global fallback when a corner exits the halo (|off|>=1).
// ---------------------------------------------------------------------------
template<int K, int PAD, int HALO>
__global__ __launch_bounds__(256) void k_sconv(
    const _Float16* __restrict__ xin, const float* __restrict__ offp,
    const _Float16* __restrict__ wtb, const float* __restrict__ bias,
    _Float16* __restrict__ outp)
{
    constexpr int KK = K * K;
    constexpr int RB = 16 + 2 * HALO;     // staged rows
    constexpr int WB = 8  + 2 * HALO;     // staged cols

    __shared__ half8v sm[RB * WB * 8];    // 16B slot per (pixel, plane)

    int bi  = blockIdx.x;
    int b   = bi / 288;                   // 288 = 12 row-tiles * 24 col-tiles
    int tt  = bi % 288;
    int by0 = (tt / 24) * 16;
    int bx0 = (tt % 24) * 8;
    int ry0 = by0 - HALO;
    int rx0 = bx0 - HALO;

    const _Float16* xb  = xin + (size_t)b * HW * 64;

    // ---- stage tile + halo (edge-clamped rows/cols) ----
    constexpr int CH = RB * WB * 8;       // 16B chunks
    for (int i = threadIdx.x; i < CH; i += 256) {
        int cc = i % WB;
        int rp = i / WB;
        int pl = rp & 7;
        int r  = rp >> 3;
        int yr = min(max(ry0 + r,  0), HH - 1);
        int xc = min(max(rx0 + cc, 0), WID - 1);
        half8v ch = *(const half8v*)(xb + ((size_t)pl * HW + (size_t)(yr * WID + xc)) * 8);
        int pix = r * WB + cc;
        sm[pix * 8 + (pl ^ (pix & 7))] = ch;
    }
    __syncthreads();

    int t    = threadIdx.x;
    int lane = t & 63;
    int wave = t >> 6;                    // 0..3 -> rows wave*4..wave*4+3
    int l31  = lane & 31;                 // position index within wave tile
    int h    = lane >> 5;                 // K-half (channel chunk parity)
    int prow = l31 >> 3;                  // 0..3
    int pcol = l31 & 7;                   // 0..7

    int yt = by0 + wave * 4 + prow;
    int xt = bx0 + pcol;
    int gp = b * HW + yt * WID + xt;

    const half8v* wbase = (const half8v*)wtb;

    f32x16 acc0 = {0.f,0.f,0.f,0.f,0.f,0.f,0.f,0.f,0.f,0.f,0.f,0.f,0.f,0.f,0.f,0.f};
    f32x16 acc1 = {0.f,0.f,0.f,0.f,0.f,0.f,0.f,0.f,0.f,0.f,0.f,0.f,0.f,0.f,0.f,0.f};

    const float2* offj = (const float2*)offp + gp;
    float2 offc = offj[0];

    int ki = 0, kj = 0;
    for (int k = 0; k < KK; k++) {
        // prefetch next tap's offset (one tap of cover, v1-proven)
        float2 offn = offj[(size_t)(k + 1) * NPOS];

        // A-frags, fragment-major: wt[k][cs][o] -> lane-contiguous 16B
        half8v a0[4], a1[4];
#pragma unroll
        for (int m = 0; m < 4; m++) {
            int cs = m * 2 + h;
            const half8v* wp = wbase + ((size_t)k * 8 + cs) * 64;   // OP = 64
            a0[m] = wp[l31];
            a1[m] = wp[32 + l31];
        }

        // per-lane sample coordinates (ONE position per lane-pair)
        float py = (float)(yt + ki - PAD) + offc.x;
        float px = (float)(xt + kj - PAD) + offc.y;
        float fy = floorf(py), fx = floorf(px);
        float wy = py - fy, wx = px - fx;
        int iy0 = (int)fy, ix0 = (int)fx;
        int iy1 = iy0 + 1, ix1 = ix0 + 1;
        float m00 = (iy0 >= 0 && iy0 < HH && ix0 >= 0 && ix0 < WID) ? 1.f : 0.f;
        float m01 = (iy0 >= 0 && iy0 < HH && ix1 >= 0 && ix1 < WID) ? 1.f : 0.f;
        float m10 = (iy1 >= 0 && iy1 < HH && ix0 >= 0 && ix0 < WID) ? 1.f : 0.f;
        float m11 = (iy1 >= 0 && iy1 < HH && ix1 >= 0 && ix1 < WID) ? 1.f : 0.f;
        half8v w00v = splat8((_Float16)((1.f - wy) * (1.f - wx) * m00));
        half8v w01v = splat8((_Float16)((1.f - wy) * wx * m01));
        half8v w10v = splat8((_Float16)(wy * (1.f - wx) * m10));
        half8v w11v = splat8((_Float16)(wy * wx * m11));

        bool fast = (iy0 >= ry0) && (iy1 <= ry0 + RB - 1) &&
                    (ix0 >= rx0) && (ix1 <= rx0 + WB - 1);

        if (__builtin_expect(fast, 1)) {
            int p00 = (iy0 - ry0) * WB + (ix0 - rx0);
            int p01 = p00 + 1, p10 = p00 + WB, p11 = p00 + WB + 1;
            int s00 = p00 & 7, s01 = p01 & 7, s10 = p10 & 7, s11 = p11 & 7;
#pragma unroll
            for (int m = 0; m < 4; m++) {
                int cs = m * 2 + h;
                half8v c00 = sm[p00 * 8 + (cs ^ s00)];
                half8v c01 = sm[p01 * 8 + (cs ^ s01)];
                half8v c10 = sm[p10 * 8 + (cs ^ s10)];
                half8v c11 = sm[p11 * 8 + (cs ^ s11)];
                half8v bf = c00 * w00v + c01 * w01v + c10 * w10v + c11 * w11v;
                acc0 = __builtin_amdgcn_mfma_f32_32x32x16_f16(a0[m], bf, acc0, 0, 0, 0);
                acc1 = __builtin_amdgcn_mfma_f32_32x32x16_f16(a1[m], bf, acc1, 0, 0, 0);
            }
        } else {
            int cy0 = min(max(iy0, 0), HH - 1), cy1 = min(max(iy1, 0), HH - 1);
            int cx0 = min(max(ix0, 0), WID - 1), cx1 = min(max(ix1, 0), WID - 1);
            size_t i00 = (size_t)(cy0 * WID + cx0) * 8, i01 = (size_t)(cy0 * WID + cx1) * 8;
            size_t i10 = (size_t)(cy1 * WID + cx0) * 8, i11 = (size_t)(cy1 * WID + cx1) * 8;
#pragma unroll
            for (int m = 0; m < 4; m++) {
                const _Float16* xq = xb + (size_t)(m * 2 + h) * HW * 8;
                half8v c00 = *(const half8v*)(xq + i00);
                half8v c01 = *(const half8v*)(xq + i01);
                half8v c10 = *(const half8v*)(xq + i10);
                half8v c11 = *(const half8v*)(xq + i11);
                half8v bf = c00 * w00v + c01 * w01v + c10 * w10v + c11 * w11v;
                acc0 = __builtin_amdgcn_mfma_f32_32x32x16_f16(a0[m], bf, acc0, 0, 0, 0);
                acc1 = __builtin_amdgcn_mfma_f32_32x32x16_f16(a1[m], bf, acc1, 0, 0, 0);
            }
        }

        offc = offn;
        kj++;
        if (kj == K) { kj = 0; ki++; }
    }

    // ---- epilogue: D: pos = l31, o = t*32 + (reg&3) + 8*(reg>>2) + 4*h ----
    int hwp = yt * WID + xt;
    _Float16* ob = outp + (size_t)b * HW * 64 + (size_t)hwp * 8 + 4 * h;
#pragma unroll
    for (int g = 0; g < 4; g++) {
        // tile 0: o = g*8 + 4h + i, plane = g
        float4 bb0 = *(const float4*)&bias[g * 8 + 4 * h];
        half4v r0;
        r0[0] = (_Float16)(acc0[g * 4 + 0] + bb0.x);
        r0[1] = (_Float16)(acc0[g * 4 + 1] + bb0.y);
        r0[2] = (_Float16)(acc0[g * 4 + 2] + bb0.z);
        r0[3] = (_Float16)(acc0[g * 4 + 3] + bb0.w);
        *(half4v*)&ob[(size_t)g * HW * 8] = r0;
        // tile 1: o = 32 + g*8 + 4h + i, plane = 4 + g
        float4 bb1 = *(const float4*)&bias[32 + g * 8 + 4 * h];
        half4v r1;
        r1[0] = (_Float16)(acc1[g * 4 + 0] + bb1.x);
        r1[1] = (_Float16)(acc1[g * 4 + 1] + bb1.y);
        r1[2] = (_Float16)(acc1[g * 4 + 2] + bb1.z);
        r1[3] = (_Float16)(acc1[g * 4 + 3] + bb1.w);
        *(half4v*)&ob[(size_t)(4 + g) * HW * 8] = r1;
    }
}

// ---------------------------------------------------------------------------
// k_soconv v2: LDS-staged REGULAR conv for the offset branches, 32x32x16
// MFMA, fragment-major coalesced weights (round 7's 32-line/instr weight
// scatter was the measured bottleneck: VALU 3%, MFMA 7%, all pipes idle,
// ~7.5 GB of L2->L1 line traffic). Zero-fill staging (conv semantics),
// window reads always in staged region (HALO = PAD), no bilinear.
// Epilogue: tap-major float2 offset planes, pair-guarded by t0 < KTAP.
// ---------------------------------------------------------------------------
template<int K, int PAD, int NTILE, int CO>
__global__ __launch_bounds__(256) void k_soconv(
    const _Float16* __restrict__ xin,
    const _Float16* __restrict__ wtb, const float* __restrict__ bias,
    float* __restrict__ outf)
{
    constexpr int KK = K * K;
    constexpr int KTAP = CO / 2;
    constexpr int HALO = PAD;
    constexpr int RB = 16 + 2 * HALO;
    constexpr int WB = 8  + 2 * HALO;
    constexpr int OP = NTILE * 32;

    __shared__ half8v sm[RB * WB * 8];

    int bi  = blockIdx.x;
    int b   = bi / 288;
    int tt  = bi % 288;
    int by0 = (tt / 24) * 16;
    int bx0 = (tt % 24) * 8;
    int ry0 = by0 - HALO;
    int rx0 = bx0 - HALO;

    const _Float16* xb = xin + (size_t)b * HW * 64;

    // ---- stage tile + halo, ZERO-FILL outside the image ----
    constexpr int CH = RB * WB * 8;
    for (int i = threadIdx.x; i < CH; i += 256) {
        int cc = i % WB;
        int rp = i / WB;
        int pl = rp & 7;
        int r  = rp >> 3;
        int yr = ry0 + r;
        int xc = rx0 + cc;
        bool ok = (yr >= 0 && yr < HH && xc >= 0 && xc < WID);
        half8v ch = ok ? *(const half8v*)(xb + ((size_t)pl * HW + (size_t)(yr * WID + xc)) * 8)
                       : splat8((_Float16)0.f);
        int pix = r * WB + cc;
        sm[pix * 8 + (pl ^ (pix & 7))] = ch;
    }
    __syncthreads();

    int lane = threadIdx.x & 63;
    int wave = threadIdx.x >> 6;          // 0..3
    int l31  = lane & 31;
    int h    = lane >> 5;
    int prow = l31 >> 3;
    int pcol = l31 & 7;

    int yt = by0 + wave * 4 + prow;
    int xt = bx0 + pcol;
    int gp = b * HW + yt * WID + xt;

    const half8v* wbase = (const half8v*)wtb;

    f32x16 acc[NTILE];
#pragma unroll
    for (int tI = 0; tI < NTILE; tI++)
#pragma unroll
        for (int r = 0; r < 16; r++) acc[tI][r] = 0.f;

    int ki = 0, kj = 0;
    for (int k = 0; k < KK; k++) {
        // window pixel for this tap: always inside the staged region
        int rr  = (yt + ki - PAD) - ry0;     // in [0, RB)
        int ccx = (xt + kj - PAD) - rx0;     // in [0, WB)
        int pix = rr * WB + ccx;
        int s   = pix & 7;

#pragma unroll
        for (int m = 0; m < 4; m++) {
            int cs = m * 2 + h;
            half8v bf = sm[pix * 8 + (cs ^ s)];
            const half8v* wp = wbase + ((size_t)k * 8 + cs) * OP;
#pragma unroll
            for (int tI = 0; tI < NTILE; tI++) {
                half8v a = wp[tI * 32 + l31];
                acc[tI] = __builtin_amdgcn_mfma_f32_32x32x16_f16(a, bf, acc[tI], 0, 0, 0);
            }
        }

        kj++;
        if (kj == K) { kj = 0; ki++; }
    }

    // ---- epilogue: tap-major float2 planes, o = tile*32 + i + 8g + 4h ----
#pragma unroll
    for (int tI = 0; tI < NTILE; tI++) {
#pragma unroll
        for (int g = 0; g < 4; g++) {
            int base = tI * 32 + 8 * g + 4 * h;
#pragma unroll
            for (int pr = 0; pr < 2; pr++) {
                int o  = base + 2 * pr;
                int t0 = o >> 1;
                if (t0 < KTAP) {
                    float2 r;
                    r.x = acc[tI][g * 4 + 2 * pr]     + bias[o];
                    r.y = acc[tI][g * 4 + 2 * pr + 1] + bias[o + 1];
                    *(float2*)&outf[((size_t)t0 * NPOS + gp) * 2] = r;
                }
            }
        }
    }
}

// ---------------------------------------------------------------------------
// K4: h = x1_final + x2 (plane fp16); out = h @ w_out^T + b_out + x (NCHW fp32)
// ---------------------------------------------------------------------------
__global__ __launch_bounds__(256) void k_merge_out(
    const _Float16* __restrict__ x1f, const _Float16* __restrict__ x2,
    const float* __restrict__ xin, const float* __restrict__ w_out,
    const float* __restrict__ b_out, float* __restrict__ out)
{
    int p  = blockIdx.x * 256 + threadIdx.x;
    int b  = p / HW;
    int hw = p % HW;

    const _Float16* a1 = x1f + (size_t)b * HW * 64 + (size_t)hw * 8;
    const _Float16* a2 = x2  + (size_t)b * HW * 64 + (size_t)hw * 8;
    float v[64];
#pragma unroll
    for (int pl = 0; pl < 8; pl++) {
        half8v u1 = *(const half8v*)&a1[(size_t)pl * HW * 8];
        half8v u2 = *(const half8v*)&a2[(size_t)pl * HW * 8];
#pragma unroll
        for (int j = 0; j < 8; j++)
            v[pl * 8 + j] = (float)u1[j] + (float)u2[j];
    }

    size_t base = (size_t)b * CB * HW + hw;
    for (int o = 0; o < 64; o++) {
        float a = b_out[o] + xin[base + (size_t)o * HW];
#pragma unroll
        for (int c = 0; c < 64; c++) a += v[c] * w_out[o * 64 + c];
        out[base + (size_t)o * HW] = a;
    }
}

// ---------------------------------------------------------------------------
// Launch. Workspace: x1a/x1b/x2 plane fp16 (18.9 MB each), off tap-major
// float2 planes (50 planes * NPOS * 8B = 59 MB), fp16 weights (~1.4 MB,
// fragment-major; wto1 padded to OP=128).
// ---------------------------------------------------------------------------
extern "C" void kernel_launch(void* const* d_in, const int* in_sizes, int n_in,
                              void* d_out, int out_size, void* d_ws, size_t ws_size,
                              hipStream_t stream)
{
    const float* x     = (const float*)d_in[0];
    const float* ln_w  = (const float*)d_in[1];
    const float* ln_b  = (const float*)d_in[2];
    const float* w_in  = (const float*)d_in[3];
    const float* b_in  = (const float*)d_in[4];
    const float* w_out = (const float*)d_in[5];
    const float* b_out = (const float*)d_in[6];
    const float* dw1   = (const float*)d_in[7];
    const float* db1   = (const float*)d_in[8];
    const float* dw2   = (const float*)d_in[9];
    const float* db2   = (const float*)d_in[10];
    const float* dw3   = (const float*)d_in[11];
    const float* db3   = (const float*)d_in[12];
    const float* ow1   = (const float*)d_in[13];
    const float* ob1   = (const float*)d_in[14];
    const float* ow2   = (const float*)d_in[15];
    const float* ob2   = (const float*)d_in[16];
    const float* ow3   = (const float*)d_in[17];
    const float* ob3   = (const float*)d_in[18];

    _Float16* x1a = (_Float16*)d_ws;
    _Float16* x1b = x1a + (size_t)NPOS * 64;
    _Float16* x2  = x1b + (size_t)NPOS * 64;
    float* off = (float*)(x2 + (size_t)NPOS * 64);
    _Float16* wtd1 = (_Float16*)(off + (size_t)NPOS * 100);
    _Float16* wtd2 = wtd1 + 49 * 64 * 64;
    _Float16* wtd3 = wtd2 + 25 * 64 * 64;
    _Float16* wto1 = wtd3 +  9 * 64 * 64;
    _Float16* wto2 = wto1 + 25 * 128 * 64;   // OP=128
    _Float16* wto3 = wto2 + 25 * 64 * 64;

    // weight prep (fp16, fragment-major [tap][cs][o][8ch])
    k_wth<49, 64,  64><<<784, 256, 0, stream>>>(dw1, wtd1);
    k_wth<25, 64,  64><<<400, 256, 0, stream>>>(dw2, wtd2);
    k_wth< 9, 64,  64><<<144, 256, 0, stream>>>(dw3, wtd3);
    k_wth<25, 98, 128><<<800, 256, 0, stream>>>(ow1, wto1);
    k_wth<25, 50,  64><<<400, 256, 0, stream>>>(ow2, wto2);
    k_wth< 9, 18,  32><<< 72, 256, 0, stream>>>(ow3, wto3);

    k_ln_conv_in<<<NPOS / 256, 256, 0, stream>>>(x, ln_w, ln_b, w_in, b_in, x1a, x2);

    // offset convs: LDS-staged k_soconv v2 (coalesced weights)
    // deform convs: LDS-staged k_sconv v7 (coalesced weights)
    // stage 1
    k_soconv<5, 2, 4, 98><<<1152, 256, 0, stream>>>(x1a, wto1, ob1, off);
    k_sconv<7, 3, 4><<<1152, 256, 0, stream>>>(x1a, off, wtd1, db1, x1b);
    // stage 2
    k_soconv<5, 2, 2, 50><<<1152, 256, 0, stream>>>(x1b, wto2, ob2, off);
    k_sconv<5, 2, 3><<<1152, 256, 0, stream>>>(x1b, off, wtd2, db2, x1a);
    // stage 3
    k_soconv<3, 1, 1, 18><<<1152, 256, 0, stream>>>(x1a, wto3, ob3, off);
    k_sconv<3, 1, 2><<<1152, 256, 0, stream>>>(x1a, off, wtd3, db3, x1b);

    k_merge_out<<<NPOS / 256, 256, 0, stream>>>(x1b, x2, x, w_out, b_out, (float*)d_out);
}

// Round 9
// 603.973 us; speedup vs baseline: 1.9874x; 1.2333x over previous
//
#include <hip/hip_runtime.h>

// Problem constants (B=4, C=64, H=W=192)
#define HH 192
#define WID 192
#define HW (HH*WID)          // 36864
#define CB 64
#define BB 4
#define NPOS (BB*HW)         // 147456

typedef __attribute__((ext_vector_type(8))) _Float16 half8v;
typedef __attribute__((ext_vector_type(4))) _Float16 half4v;
typedef __attribute__((ext_vector_type(4))) float f32x4;
typedef __attribute__((ext_vector_type(16))) float f32x16;

static __device__ inline half8v splat8(_Float16 x) {
    half8v v = {x, x, x, x, x, x, x, x};
    return v;
}

// x tensors: CHANNEL-PLANE fp16 layout x[b][plane=c>>3][hw][8ch] (16B/pos/plane).
// Offsets: TAP-MAJOR float2 planes off[k][global_pos][2] (NPOS float2 per plane).
// Weights: FRAGMENT-MAJOR fp16 wt[k][cs][o][8ch], cs = 8-channel chunk.
// A-frag load = wbase[(k*8+cs)*OP + o_idx] -> 32 consecutive lanes read 512B
// contiguous (round-8 fix for the L2-line-traffic bottleneck).

// ---------------------------------------------------------------------------
// Weight prep: w[o][c][ki][kj] fp32 (OIHW) -> wt[k][cs][o][j] fp16
// (fragment-major; o padded to OP; c = cs*8 + j). KK=1 handles 1x1 convs.
// ---------------------------------------------------------------------------
template<int KK, int CO, int OP>
__global__ void k_wth(const float* __restrict__ w, _Float16* __restrict__ wt)
{
    int idx = blockIdx.x * 256 + threadIdx.x;
    constexpr int TOT = KK * OP * 64;
    if (idx >= TOT) return;
    int k  = idx / (OP * 64);
    int r  = idx % (OP * 64);
    int cs = r / (OP * 8);
    int r2 = r % (OP * 8);
    int o  = r2 / 8;
    int j  = r2 % 8;
    int c  = cs * 8 + j;
    float v = (o < CO) ? w[((size_t)o * 64 + c) * KK + k] : 0.f;
    wt[idx] = (_Float16)v;
}

// ---------------------------------------------------------------------------
// K1 (round 9, MFMA): LayerNorm over C + 1x1 conv C->2C via 32x32x16 MFMA.
// Block = 128 contiguous positions, 4 waves x 32 pos; 2 lanes/position
// (h = lane>>5 holds channel-half). LN stats pair-reduced by shfl_xor(32).
// Round-8 PMC on the scalar version: MfmaUtil 0, 167us -- a 128x64 matmul
// per position run on the scalar VALU (guide G10 violation).
// Same fragment/epilogue layout as the verified k_soconv/k_sconv.
// ---------------------------------------------------------------------------
__global__ __launch_bounds__(256) void k_lnconv_mfma(
    const float* __restrict__ x, const float* __restrict__ g, const float* __restrict__ be,
    const _Float16* __restrict__ wt_in, const float* __restrict__ b_in,
    _Float16* __restrict__ x1, _Float16* __restrict__ x2)
{
    int p0  = blockIdx.x * 128;
    int b   = p0 / HW;
    int hwb = p0 % HW;

    int lane = threadIdx.x & 63;
    int wave = threadIdx.x >> 6;
    int l31  = lane & 31;
    int h    = lane >> 5;
    int pos  = hwb + wave * 32 + l31;

    const float* xp = x + (size_t)b * CB * HW + pos;

    // this lane's 32 channels: c = m*16 + h*8 + j
    float v[32];
    float sum = 0.f, sumsq = 0.f;
#pragma unroll
    for (int m = 0; m < 4; m++)
#pragma unroll
        for (int j = 0; j < 8; j++) {
            float t = xp[(size_t)(m * 16 + h * 8 + j) * HW];
            v[m * 8 + j] = t; sum += t; sumsq += t * t;
        }
    // complete LN stats across the position's lane pair (l31 <-> l31+32)
    sum   += __shfl_xor(sum, 32);
    sumsq += __shfl_xor(sumsq, 32);
    float mu  = sum * (1.f / 64.f);
    float var = sumsq * (1.f / 64.f) - mu * mu;
    float inv = rsqrtf(var + 1e-5f);

    half8v bf[4];
#pragma unroll
    for (int m = 0; m < 4; m++)
#pragma unroll
        for (int j = 0; j < 8; j++) {
            int c = m * 16 + h * 8 + j;
            bf[m][j] = (_Float16)((v[m * 8 + j] - mu) * inv * g[c] + be[c]);
        }

    f32x16 acc[4];
#pragma unroll
    for (int tI = 0; tI < 4; tI++)
#pragma unroll
        for (int r = 0; r < 16; r++) acc[tI][r] = 0.f;

    const half8v* wbase = (const half8v*)wt_in;
#pragma unroll
    for (int m = 0; m < 4; m++) {
        int cs = m * 2 + h;
        const half8v* wp = wbase + (size_t)cs * 128;      // OP = 128
#pragma unroll
        for (int tI = 0; tI < 4; tI++) {
            half8v a = wp[tI * 32 + l31];
            acc[tI] = __builtin_amdgcn_mfma_f32_32x32x16_f16(a, bf[m], acc[tI], 0, 0, 0);
        }
    }

    // epilogue: o = tI*32 + (r&3) + 8*(r>>2) + 4h; tiles 0-1 -> x1, 2-3 -> x2
    _Float16* o1 = x1 + (size_t)b * HW * 64 + (size_t)pos * 8;
    _Float16* o2 = x2 + (size_t)b * HW * 64 + (size_t)pos * 8;
#pragma unroll
    for (int tI = 0; tI < 4; tI++) {
        _Float16* ob = (tI < 2) ? o1 : o2;
        int obase = (tI & 1) * 32;
#pragma unroll
        for (int gidx = 0; gidx < 4; gidx++) {
            int o = obase + gidx * 8 + 4 * h;             // within 64-ch tensor
            float4 bb = *(const float4*)&b_in[tI * 32 + gidx * 8 + 4 * h];
            half4v r;
            r[0] = (_Float16)(acc[tI][gidx * 4 + 0] + bb.x);
            r[1] = (_Float16)(acc[tI][gidx * 4 + 1] + bb.y);
            r[2] = (_Float16)(acc[tI][gidx * 4 + 2] + bb.z);
            r[3] = (_Float16)(acc[tI][gidx * 4 + 3] + bb.w);
            *(half4v*)&ob[(size_t)(o >> 3) * HW * 8 + (o & 7)] = r;
        }
    }
}

// ---------------------------------------------------------------------------
// k_sconv v7 (unchanged from round 8): LDS-staged deform conv, 32x32x16 MFMA,
// fragment-major weights. 16x8-position block, 256 thr, grid 1152.
// ---------------------------------------------------------------------------
template<int K, int PAD, int HALO>
__global__ __launch_bounds__(256) void k_sconv(
    const _Float16* __restrict__ xin, const float* __restrict__ offp,
    const _Float16* __restrict__ wtb, const float* __restrict__ bias,
    _Float16* __restrict__ outp)
{
    constexpr int KK = K * K;
    constexpr int RB = 16 + 2 * HALO;     // staged rows
    constexpr int WB = 8  + 2 * HALO;     // staged cols

    __shared__ half8v sm[RB * WB * 8];    // 16B slot per (pixel, plane)

    int bi  = blockIdx.x;
    int b   = bi / 288;                   // 288 = 12 row-tiles * 24 col-tiles
    int tt  = bi % 288;
    int by0 = (tt / 24) * 16;
    int bx0 = (tt % 24) * 8;
    int ry0 = by0 - HALO;
    int rx0 = bx0 - HALO;

    const _Float16* xb  = xin + (size_t)b * HW * 64;

    // ---- stage tile + halo (edge-clamped rows/cols) ----
    constexpr int CH = RB * WB * 8;       // 16B chunks
    for (int i = threadIdx.x; i < CH; i += 256) {
        int cc = i % WB;
        int rp = i / WB;
        int pl = rp & 7;
        int r  = rp >> 3;
        int yr = min(max(ry0 + r,  0), HH - 1);
        int xc = min(max(rx0 + cc, 0), WID - 1);
        half8v ch = *(const half8v*)(xb + ((size_t)pl * HW + (size_t)(yr * WID + xc)) * 8);
        int pix = r * WB + cc;
        sm[pix * 8 + (pl ^ (pix & 7))] = ch;
    }
    __syncthreads();

    int t    = threadIdx.x;
    int lane = t & 63;
    int wave = t >> 6;                    // 0..3 -> rows wave*4..wave*4+3
    int l31  = lane & 31;                 // position index within wave tile
    int h    = lane >> 5;                 // K-half (channel chunk parity)
    int prow = l31 >> 3;                  // 0..3
    int pcol = l31 & 7;                   // 0..7

    int yt = by0 + wave * 4 + prow;
    int xt = bx0 + pcol;
    int gp = b * HW + yt * WID + xt;

    const half8v* wbase = (const half8v*)wtb;

    f32x16 acc0 = {0.f,0.f,0.f,0.f,0.f,0.f,0.f,0.f,0.f,0.f,0.f,0.f,0.f,0.f,0.f,0.f};
    f32x16 acc1 = {0.f,0.f,0.f,0.f,0.f,0.f,0.f,0.f,0.f,0.f,0.f,0.f,0.f,0.f,0.f,0.f};

    const float2* offj = (const float2*)offp + gp;
    float2 offc = offj[0];

    int ki = 0, kj = 0;
    for (int k = 0; k < KK; k++) {
        // prefetch next tap's offset (one tap of cover, v1-proven)
        float2 offn = offj[(size_t)(k + 1) * NPOS];

        // A-frags, fragment-major: wt[k][cs][o] -> lane-contiguous 16B
        half8v a0[4], a1[4];
#pragma unroll
        for (int m = 0; m < 4; m++) {
            int cs = m * 2 + h;
            const half8v* wp = wbase + ((size_t)k * 8 + cs) * 64;   // OP = 64
            a0[m] = wp[l31];
            a1[m] = wp[32 + l31];
        }

        // per-lane sample coordinates (ONE position per lane-pair)
        float py = (float)(yt + ki - PAD) + offc.x;
        float px = (float)(xt + kj - PAD) + offc.y;
        float fy = floorf(py), fx = floorf(px);
        float wy = py - fy, wx = px - fx;
        int iy0 = (int)fy, ix0 = (int)fx;
        int iy1 = iy0 + 1, ix1 = ix0 + 1;
        float m00 = (iy0 >= 0 && iy0 < HH && ix0 >= 0 && ix0 < WID) ? 1.f : 0.f;
        float m01 = (iy0 >= 0 && iy0 < HH && ix1 >= 0 && ix1 < WID) ? 1.f : 0.f;
        float m10 = (iy1 >= 0 && iy1 < HH && ix0 >= 0 && ix0 < WID) ? 1.f : 0.f;
        float m11 = (iy1 >= 0 && iy1 < HH && ix1 >= 0 && ix1 < WID) ? 1.f : 0.f;
        half8v w00v = splat8((_Float16)((1.f - wy) * (1.f - wx) * m00));
        half8v w01v = splat8((_Float16)((1.f - wy) * wx * m01));
        half8v w10v = splat8((_Float16)(wy * (1.f - wx) * m10));
        half8v w11v = splat8((_Float16)(wy * wx * m11));

        bool fast = (iy0 >= ry0) && (iy1 <= ry0 + RB - 1) &&
                    (ix0 >= rx0) && (ix1 <= rx0 + WB - 1);

        if (__builtin_expect(fast, 1)) {
            int p00 = (iy0 - ry0) * WB + (ix0 - rx0);
            int p01 = p00 + 1, p10 = p00 + WB, p11 = p00 + WB + 1;
            int s00 = p00 & 7, s01 = p01 & 7, s10 = p10 & 7, s11 = p11 & 7;
#pragma unroll
            for (int m = 0; m < 4; m++) {
                int cs = m * 2 + h;
                half8v c00 = sm[p00 * 8 + (cs ^ s00)];
                half8v c01 = sm[p01 * 8 + (cs ^ s01)];
                half8v c10 = sm[p10 * 8 + (cs ^ s10)];
                half8v c11 = sm[p11 * 8 + (cs ^ s11)];
                half8v bf = c00 * w00v + c01 * w01v + c10 * w10v + c11 * w11v;
                acc0 = __builtin_amdgcn_mfma_f32_32x32x16_f16(a0[m], bf, acc0, 0, 0, 0);
                acc1 = __builtin_amdgcn_mfma_f32_32x32x16_f16(a1[m], bf, acc1, 0, 0, 0);
            }
        } else {
            int cy0 = min(max(iy0, 0), HH - 1), cy1 = min(max(iy1, 0), HH - 1);
            int cx0 = min(max(ix0, 0), WID - 1), cx1 = min(max(ix1, 0), WID - 1);
            size_t i00 = (size_t)(cy0 * WID + cx0) * 8, i01 = (size_t)(cy0 * WID + cx1) * 8;
            size_t i10 = (size_t)(cy1 * WID + cx0) * 8, i11 = (size_t)(cy1 * WID + cx1) * 8;
#pragma unroll
            for (int m = 0; m < 4; m++) {
                const _Float16* xq = xb + (size_t)(m * 2 + h) * HW * 8;
                half8v c00 = *(const half8v*)(xq + i00);
                half8v c01 = *(const half8v*)(xq + i01);
                half8v c10 = *(const half8v*)(xq + i10);
                half8v c11 = *(const half8v*)(xq + i11);
                half8v bf = c00 * w00v + c01 * w01v + c10 * w10v + c11 * w11v;
                acc0 = __builtin_amdgcn_mfma_f32_32x32x16_f16(a0[m], bf, acc0, 0, 0, 0);
                acc1 = __builtin_amdgcn_mfma_f32_32x32x16_f16(a1[m], bf, acc1, 0, 0, 0);
            }
        }

        offc = offn;
        kj++;
        if (kj == K) { kj = 0; ki++; }
    }

    // ---- epilogue: D: pos = l31, o = t*32 + (reg&3) + 8*(reg>>2) + 4*h ----
    int hwp = yt * WID + xt;
    _Float16* ob = outp + (size_t)b * HW * 64 + (size_t)hwp * 8 + 4 * h;
#pragma unroll
    for (int g = 0; g < 4; g++) {
        float4 bb0 = *(const float4*)&bias[g * 8 + 4 * h];
        half4v r0;
        r0[0] = (_Float16)(acc0[g * 4 + 0] + bb0.x);
        r0[1] = (_Float16)(acc0[g * 4 + 1] + bb0.y);
        r0[2] = (_Float16)(acc0[g * 4 + 2] + bb0.z);
        r0[3] = (_Float16)(acc0[g * 4 + 3] + bb0.w);
        *(half4v*)&ob[(size_t)g * HW * 8] = r0;
        float4 bb1 = *(const float4*)&bias[32 + g * 8 + 4 * h];
        half4v r1;
        r1[0] = (_Float16)(acc1[g * 4 + 0] + bb1.x);
        r1[1] = (_Float16)(acc1[g * 4 + 1] + bb1.y);
        r1[2] = (_Float16)(acc1[g * 4 + 2] + bb1.z);
        r1[3] = (_Float16)(acc1[g * 4 + 3] + bb1.w);
        *(half4v*)&ob[(size_t)(4 + g) * HW * 8] = r1;
    }
}

// ---------------------------------------------------------------------------
// k_soconv v2 (unchanged from round 8): LDS-staged regular conv for offset
// branches, 32x32x16 MFMA, fragment-major weights, zero-fill staging.
// ---------------------------------------------------------------------------
template<int K, int PAD, int NTILE, int CO>
__global__ __launch_bounds__(256) void k_soconv(
    const _Float16* __restrict__ xin,
    const _Float16* __restrict__ wtb, const float* __restrict__ bias,
    float* __restrict__ outf)
{
    constexpr int KK = K * K;
    constexpr int KTAP = CO / 2;
    constexpr int HALO = PAD;
    constexpr int RB = 16 + 2 * HALO;
    constexpr int WB = 8  + 2 * HALO;
    constexpr int OP = NTILE * 32;

    __shared__ half8v sm[RB * WB * 8];

    int bi  = blockIdx.x;
    int b   = bi / 288;
    int tt  = bi % 288;
    int by0 = (tt / 24) * 16;
    int bx0 = (tt % 24) * 8;
    int ry0 = by0 - HALO;
    int rx0 = bx0 - HALO;

    const _Float16* xb = xin + (size_t)b * HW * 64;

    // ---- stage tile + halo, ZERO-FILL outside the image ----
    constexpr int CH = RB * WB * 8;
    for (int i = threadIdx.x; i < CH; i += 256) {
        int cc = i % WB;
        int rp = i / WB;
        int pl = rp & 7;
        int r  = rp >> 3;
        int yr = ry0 + r;
        int xc = rx0 + cc;
        bool ok = (yr >= 0 && yr < HH && xc >= 0 && xc < WID);
        half8v ch = ok ? *(const half8v*)(xb + ((size_t)pl * HW + (size_t)(yr * WID + xc)) * 8)
                       : splat8((_Float16)0.f);
        int pix = r * WB + cc;
        sm[pix * 8 + (pl ^ (pix & 7))] = ch;
    }
    __syncthreads();

    int lane = threadIdx.x & 63;
    int wave = threadIdx.x >> 6;          // 0..3
    int l31  = lane & 31;
    int h    = lane >> 5;
    int prow = l31 >> 3;
    int pcol = l31 & 7;

    int yt = by0 + wave * 4 + prow;
    int xt = bx0 + pcol;
    int gp = b * HW + yt * WID + xt;

    const half8v* wbase = (const half8v*)wtb;

    f32x16 acc[NTILE];
#pragma unroll
    for (int tI = 0; tI < NTILE; tI++)
#pragma unroll
        for (int r = 0; r < 16; r++) acc[tI][r] = 0.f;

    int ki = 0, kj = 0;
    for (int k = 0; k < KK; k++) {
        int rr  = (yt + ki - PAD) - ry0;     // in [0, RB)
        int ccx = (xt + kj - PAD) - rx0;     // in [0, WB)
        int pix = rr * WB + ccx;
        int s   = pix & 7;

#pragma unroll
        for (int m = 0; m < 4; m++) {
            int cs = m * 2 + h;
            half8v bf = sm[pix * 8 + (cs ^ s)];
            const half8v* wp = wbase + ((size_t)k * 8 + cs) * OP;
#pragma unroll
            for (int tI = 0; tI < NTILE; tI++) {
                half8v a = wp[tI * 32 + l31];
                acc[tI] = __builtin_amdgcn_mfma_f32_32x32x16_f16(a, bf, acc[tI], 0, 0, 0);
            }
        }

        kj++;
        if (kj == K) { kj = 0; ki++; }
    }

    // ---- epilogue: tap-major float2 planes, o = tile*32 + i + 8g + 4h ----
#pragma unroll
    for (int tI = 0; tI < NTILE; tI++) {
#pragma unroll
        for (int g = 0; g < 4; g++) {
            int base = tI * 32 + 8 * g + 4 * h;
#pragma unroll
            for (int pr = 0; pr < 2; pr++) {
                int o  = base + 2 * pr;
                int t0 = o >> 1;
                if (t0 < KTAP) {
                    float2 r;
                    r.x = acc[tI][g * 4 + 2 * pr]     + bias[o];
                    r.y = acc[tI][g * 4 + 2 * pr + 1] + bias[o + 1];
                    *(float2*)&outf[((size_t)t0 * NPOS + gp) * 2] = r;
                }
            }
        }
    }
}

// ---------------------------------------------------------------------------
// K4 (round 9, MFMA): h = x1_final + x2; out = h @ w_out^T + b_out + x.
// Block = 128 positions, 4 waves x 32 pos; 2 tiles of 32 outs; coalesced
// half8v B-frag loads from the plane layout; fp32 NCHW output + residual.
// ---------------------------------------------------------------------------
__global__ __launch_bounds__(256) void k_merge_mfma(
    const _Float16* __restrict__ x1f, const _Float16* __restrict__ x2,
    const float* __restrict__ xin, const _Float16* __restrict__ wt_out,
    const float* __restrict__ b_out, float* __restrict__ out)
{
    int p0  = blockIdx.x * 128;
    int b   = p0 / HW;
    int hwb = p0 % HW;

    int lane = threadIdx.x & 63;
    int wave = threadIdx.x >> 6;
    int l31  = lane & 31;
    int h    = lane >> 5;
    int pos  = hwb + wave * 32 + l31;

    const _Float16* a1 = x1f + (size_t)b * HW * 64 + (size_t)pos * 8;
    const _Float16* a2 = x2  + (size_t)b * HW * 64 + (size_t)pos * 8;

    half8v bf[4];
#pragma unroll
    for (int m = 0; m < 4; m++) {
        int cs = m * 2 + h;
        half8v u1 = *(const half8v*)&a1[(size_t)cs * HW * 8];
        half8v u2 = *(const half8v*)&a2[(size_t)cs * HW * 8];
        bf[m] = u1 + u2;
    }

    f32x16 acc[2];
#pragma unroll
    for (int tI = 0; tI < 2; tI++)
#pragma unroll
        for (int r = 0; r < 16; r++) acc[tI][r] = 0.f;

    const half8v* wbase = (const half8v*)wt_out;
#pragma unroll
    for (int m = 0; m < 4; m++) {
        int cs = m * 2 + h;
        const half8v* wp = wbase + (size_t)cs * 64;       // OP = 64
#pragma unroll
        for (int tI = 0; tI < 2; tI++) {
            half8v a = wp[tI * 32 + l31];
            acc[tI] = __builtin_amdgcn_mfma_f32_32x32x16_f16(a, bf[m], acc[tI], 0, 0, 0);
        }
    }

    // epilogue: o = tI*32 + gidx*8 + 4h + i; out = acc + bias + residual
    size_t base = (size_t)b * CB * HW + pos;
#pragma unroll
    for (int tI = 0; tI < 2; tI++) {
#pragma unroll
        for (int gidx = 0; gidx < 4; gidx++) {
            int o0 = tI * 32 + gidx * 8 + 4 * h;
#pragma unroll
            for (int i = 0; i < 4; i++) {
                int o = o0 + i;
                out[base + (size_t)o * HW] =
                    acc[tI][gidx * 4 + i] + b_out[o] + xin[base + (size_t)o * HW];
            }
        }
    }
}

// ---------------------------------------------------------------------------
// Launch. Workspace: x1a/x1b/x2 plane fp16 (18.9 MB each), off tap-major
// float2 planes (59 MB), fp16 weights (~1.5 MB, fragment-major; wto1 OP=128;
// + wt_in 16KB, wt_out 8KB for the 1x1 convs).
// ---------------------------------------------------------------------------
extern "C" void kernel_launch(void* const* d_in, const int* in_sizes, int n_in,
                              void* d_out, int out_size, void* d_ws, size_t ws_size,
                              hipStream_t stream)
{
    const float* x     = (const float*)d_in[0];
    const float* ln_w  = (const float*)d_in[1];
    const float* ln_b  = (const float*)d_in[2];
    const float* w_in  = (const float*)d_in[3];
    const float* b_in  = (const float*)d_in[4];
    const float* w_out = (const float*)d_in[5];
    const float* b_out = (const float*)d_in[6];
    const float* dw1   = (const float*)d_in[7];
    const float* db1   = (const float*)d_in[8];
    const float* dw2   = (const float*)d_in[9];
    const float* db2   = (const float*)d_in[10];
    const float* dw3   = (const float*)d_in[11];
    const float* db3   = (const float*)d_in[12];
    const float* ow1   = (const float*)d_in[13];
    const float* ob1   = (const float*)d_in[14];
    const float* ow2   = (const float*)d_in[15];
    const float* ob2   = (const float*)d_in[16];
    const float* ow3   = (const float*)d_in[17];
    const float* ob3   = (const float*)d_in[18];

    _Float16* x1a = (_Float16*)d_ws;
    _Float16* x1b = x1a + (size_t)NPOS * 64;
    _Float16* x2  = x1b + (size_t)NPOS * 64;
    float* off = (float*)(x2 + (size_t)NPOS * 64);
    _Float16* wtd1 = (_Float16*)(off + (size_t)NPOS * 100);
    _Float16* wtd2 = wtd1 + 49 * 64 * 64;
    _Float16* wtd3 = wtd2 + 25 * 64 * 64;
    _Float16* wto1 = wtd3 +  9 * 64 * 64;
    _Float16* wto2 = wto1 + 25 * 128 * 64;   // OP=128
    _Float16* wto3 = wto2 + 25 * 64 * 64;
    _Float16* wtin = wto3 +  9 * 32 * 64;
    _Float16* wtou = wtin + 128 * 64;

    // weight prep (fp16, fragment-major [tap][cs][o][8ch]); 1x1 convs KK=1
    k_wth<49, 64,  64><<<784, 256, 0, stream>>>(dw1, wtd1);
    k_wth<25, 64,  64><<<400, 256, 0, stream>>>(dw2, wtd2);
    k_wth< 9, 64,  64><<<144, 256, 0, stream>>>(dw3, wtd3);
    k_wth<25, 98, 128><<<800, 256, 0, stream>>>(ow1, wto1);
    k_wth<25, 50,  64><<<400, 256, 0, stream>>>(ow2, wto2);
    k_wth< 9, 18,  32><<< 72, 256, 0, stream>>>(ow3, wto3);
    k_wth< 1, 128, 128><<<32, 256, 0, stream>>>(w_in, wtin);
    k_wth< 1, 64,  64><<<16, 256, 0, stream>>>(w_out, wtou);

    // LN + 1x1 conv (MFMA)
    k_lnconv_mfma<<<NPOS / 128, 256, 0, stream>>>(x, ln_w, ln_b, wtin, b_in, x1a, x2);

    // stage 1
    k_soconv<5, 2, 4, 98><<<1152, 256, 0, stream>>>(x1a, wto1, ob1, off);
    k_sconv<7, 3, 4><<<1152, 256, 0, stream>>>(x1a, off, wtd1, db1, x1b);
    // stage 2
    k_soconv<5, 2, 2, 50><<<1152, 256, 0, stream>>>(x1b, wto2, ob2, off);
    k_sconv<5, 2, 3><<<1152, 256, 0, stream>>>(x1b, off, wtd2, db2, x1a);
    // stage 3
    k_soconv<3, 1, 1, 18><<<1152, 256, 0, stream>>>(x1a, wto3, ob3, off);
    k_sconv<3, 1, 2><<<1152, 256, 0, stream>>>(x1a, off, wtd3, db3, x1b);

    // merge + 1x1 conv + residual (MFMA)
    k_merge_mfma<<<NPOS / 128, 256, 0, stream>>>(x1b, x2, x, wtou, b_out, (float*)d_out);
}

// Round 10
// 581.776 us; speedup vs baseline: 2.0632x; 1.0382x over previous
//
#include <hip/hip_runtime.h>

// Problem constants (B=4, C=64, H=W=192)
#define HH 192
#define WID 192
#define HW (HH*WID)          // 36864
#define CB 64
#define BB 4
#define NPOS (BB*HW)         // 147456

typedef __attribute__((ext_vector_type(8))) _Float16 half8v;
typedef __attribute__((ext_vector_type(4))) _Float16 half4v;
typedef __attribute__((ext_vector_type(4))) float f32x4;
typedef __attribute__((ext_vector_type(16))) float f32x16;

static __device__ inline half8v splat8(_Float16 x) {
    half8v v = {x, x, x, x, x, x, x, x};
    return v;
}

// x tensors: CHANNEL-PLANE fp16 layout x[b][plane=c>>3][hw][8ch] (16B/pos/plane).
// Offsets: TAP-MAJOR float2 planes off[k][global_pos][2] (NPOS float2 per plane).
// Weights: FRAGMENT-MAJOR fp16 wt[k][cs][o][8ch], cs = 8-channel chunk.
// Staging (round 10): __builtin_amdgcn_global_load_lds width=16, LINEAR LDS
// dest (wave-uniform base + lane*16), swizzle applied on the SOURCE address:
// linear slot (pix,t) receives plane pl = t ^ (pix&7) -- same involution the
// readers use, so bytes land exactly where the old reg-staging put them.

// ---------------------------------------------------------------------------
// Weight prep: w[o][c][ki][kj] fp32 (OIHW) -> wt[k][cs][o][j] fp16
// (fragment-major; o padded to OP; c = cs*8 + j). KK=1 handles 1x1 convs.
// ---------------------------------------------------------------------------
template<int KK, int CO, int OP>
__global__ void k_wth(const float* __restrict__ w, _Float16* __restrict__ wt)
{
    int idx = blockIdx.x * 256 + threadIdx.x;
    constexpr int TOT = KK * OP * 64;
    if (idx >= TOT) return;
    int k  = idx / (OP * 64);
    int r  = idx % (OP * 64);
    int cs = r / (OP * 8);
    int r2 = r % (OP * 8);
    int o  = r2 / 8;
    int j  = r2 % 8;
    int c  = cs * 8 + j;
    float v = (o < CO) ? w[((size_t)o * 64 + c) * KK + k] : 0.f;
    wt[idx] = (_Float16)v;
}

// ---------------------------------------------------------------------------
// K1 (MFMA): LayerNorm over C + 1x1 conv C->2C via 32x32x16 MFMA.
// Block = 128 positions, 4 waves x 32 pos; 2 lanes/position (h = lane>>5).
// ---------------------------------------------------------------------------
__global__ __launch_bounds__(256) void k_lnconv_mfma(
    const float* __restrict__ x, const float* __restrict__ g, const float* __restrict__ be,
    const _Float16* __restrict__ wt_in, const float* __restrict__ b_in,
    _Float16* __restrict__ x1, _Float16* __restrict__ x2)
{
    int p0  = blockIdx.x * 128;
    int b   = p0 / HW;
    int hwb = p0 % HW;

    int lane = threadIdx.x & 63;
    int wave = threadIdx.x >> 6;
    int l31  = lane & 31;
    int h    = lane >> 5;
    int pos  = hwb + wave * 32 + l31;

    const float* xp = x + (size_t)b * CB * HW + pos;

    float v[32];
    float sum = 0.f, sumsq = 0.f;
#pragma unroll
    for (int m = 0; m < 4; m++)
#pragma unroll
        for (int j = 0; j < 8; j++) {
            float t = xp[(size_t)(m * 16 + h * 8 + j) * HW];
            v[m * 8 + j] = t; sum += t; sumsq += t * t;
        }
    sum   += __shfl_xor(sum, 32);
    sumsq += __shfl_xor(sumsq, 32);
    float mu  = sum * (1.f / 64.f);
    float var = sumsq * (1.f / 64.f) - mu * mu;
    float inv = rsqrtf(var + 1e-5f);

    half8v bf[4];
#pragma unroll
    for (int m = 0; m < 4; m++)
#pragma unroll
        for (int j = 0; j < 8; j++) {
            int c = m * 16 + h * 8 + j;
            bf[m][j] = (_Float16)((v[m * 8 + j] - mu) * inv * g[c] + be[c]);
        }

    f32x16 acc[4];
#pragma unroll
    for (int tI = 0; tI < 4; tI++)
#pragma unroll
        for (int r = 0; r < 16; r++) acc[tI][r] = 0.f;

    const half8v* wbase = (const half8v*)wt_in;
#pragma unroll
    for (int m = 0; m < 4; m++) {
        int cs = m * 2 + h;
        const half8v* wp = wbase + (size_t)cs * 128;      // OP = 128
#pragma unroll
        for (int tI = 0; tI < 4; tI++) {
            half8v a = wp[tI * 32 + l31];
            acc[tI] = __builtin_amdgcn_mfma_f32_32x32x16_f16(a, bf[m], acc[tI], 0, 0, 0);
        }
    }

    _Float16* o1 = x1 + (size_t)b * HW * 64 + (size_t)pos * 8;
    _Float16* o2 = x2 + (size_t)b * HW * 64 + (size_t)pos * 8;
#pragma unroll
    for (int tI = 0; tI < 4; tI++) {
        _Float16* ob = (tI < 2) ? o1 : o2;
        int obase = (tI & 1) * 32;
#pragma unroll
        for (int gidx = 0; gidx < 4; gidx++) {
            int o = obase + gidx * 8 + 4 * h;
            float4 bb = *(const float4*)&b_in[tI * 32 + gidx * 8 + 4 * h];
            half4v r;
            r[0] = (_Float16)(acc[tI][gidx * 4 + 0] + bb.x);
            r[1] = (_Float16)(acc[tI][gidx * 4 + 1] + bb.y);
            r[2] = (_Float16)(acc[tI][gidx * 4 + 2] + bb.z);
            r[3] = (_Float16)(acc[tI][gidx * 4 + 3] + bb.w);
            *(half4v*)&ob[(size_t)(o >> 3) * HW * 8 + (o & 7)] = r;
        }
    }
}

// ---------------------------------------------------------------------------
// k_sconv v8: = v7 with global_load_lds staging (direct-to-LDS, width 16).
// LDS dest linear; swizzle moved to the SOURCE address (rule #21 pattern).
// Edge-clamped sources: every lane valid, tail guarded by i < CH.
// ---------------------------------------------------------------------------
template<int K, int PAD, int HALO>
__global__ __launch_bounds__(256) void k_sconv(
    const _Float16* __restrict__ xin, const float* __restrict__ offp,
    const _Float16* __restrict__ wtb, const float* __restrict__ bias,
    _Float16* __restrict__ outp)
{
    constexpr int KK = K * K;
    constexpr int RB = 16 + 2 * HALO;     // staged rows
    constexpr int WB = 8  + 2 * HALO;     // staged cols

    __shared__ half8v sm[RB * WB * 8];    // 16B slot per (pixel, plane)

    int bi  = blockIdx.x;
    int b   = bi / 288;                   // 288 = 12 row-tiles * 24 col-tiles
    int tt  = bi % 288;
    int by0 = (tt / 24) * 16;
    int bx0 = (tt % 24) * 8;
    int ry0 = by0 - HALO;
    int rx0 = bx0 - HALO;

    const _Float16* xb  = xin + (size_t)b * HW * 64;

    // ---- stage tile + halo via global_load_lds (edge-clamped source) ----
    // linear slot i = pix*8 + t holds plane pl = t ^ (pix&7)
    {
        _Float16* smlin = (_Float16*)sm;
        constexpr int CH = RB * WB * 8;
        for (int i0 = 0; i0 < CH; i0 += 256) {
            int i     = i0 + (int)threadIdx.x;
            int wbse  = i0 + ((int)threadIdx.x & 192);   // wave-uniform chunk base
            if (i < CH) {
                int pix = i >> 3;
                int ts  = i & 7;
                int pl  = ts ^ (pix & 7);
                int r   = pix / WB;
                int cc  = pix - r * WB;
                int yr  = min(max(ry0 + r,  0), HH - 1);
                int xc  = min(max(rx0 + cc, 0), WID - 1);
                const _Float16* src = xb + ((size_t)pl * HW + (size_t)(yr * WID + xc)) * 8;
                __builtin_amdgcn_global_load_lds(src, &smlin[(size_t)wbse * 8], 16, 0, 0);
            }
        }
    }
    __syncthreads();

    int t    = threadIdx.x;
    int lane = t & 63;
    int wave = t >> 6;                    // 0..3 -> rows wave*4..wave*4+3
    int l31  = lane & 31;                 // position index within wave tile
    int h    = lane >> 5;                 // K-half (channel chunk parity)
    int prow = l31 >> 3;                  // 0..3
    int pcol = l31 & 7;                   // 0..7

    int yt = by0 + wave * 4 + prow;
    int xt = bx0 + pcol;
    int gp = b * HW + yt * WID + xt;

    const half8v* wbase = (const half8v*)wtb;

    f32x16 acc0 = {0.f,0.f,0.f,0.f,0.f,0.f,0.f,0.f,0.f,0.f,0.f,0.f,0.f,0.f,0.f,0.f};
    f32x16 acc1 = {0.f,0.f,0.f,0.f,0.f,0.f,0.f,0.f,0.f,0.f,0.f,0.f,0.f,0.f,0.f,0.f};

    const float2* offj = (const float2*)offp + gp;
    float2 offc = offj[0];

    int ki = 0, kj = 0;
    for (int k = 0; k < KK; k++) {
        // prefetch next tap's offset (one tap of cover, v1-proven)
        float2 offn = offj[(size_t)(k + 1) * NPOS];

        // A-frags, fragment-major: wt[k][cs][o] -> lane-contiguous 16B
        half8v a0[4], a1[4];
#pragma unroll
        for (int m = 0; m < 4; m++) {
            int cs = m * 2 + h;
            const half8v* wp = wbase + ((size_t)k * 8 + cs) * 64;   // OP = 64
            a0[m] = wp[l31];
            a1[m] = wp[32 + l31];
        }

        // per-lane sample coordinates (ONE position per lane-pair)
        float py = (float)(yt + ki - PAD) + offc.x;
        float px = (float)(xt + kj - PAD) + offc.y;
        float fy = floorf(py), fx = floorf(px);
        float wy = py - fy, wx = px - fx;
        int iy0 = (int)fy, ix0 = (int)fx;
        int iy1 = iy0 + 1, ix1 = ix0 + 1;
        float m00 = (iy0 >= 0 && iy0 < HH && ix0 >= 0 && ix0 < WID) ? 1.f : 0.f;
        float m01 = (iy0 >= 0 && iy0 < HH && ix1 >= 0 && ix1 < WID) ? 1.f : 0.f;
        float m10 = (iy1 >= 0 && iy1 < HH && ix0 >= 0 && ix0 < WID) ? 1.f : 0.f;
        float m11 = (iy1 >= 0 && iy1 < HH && ix1 >= 0 && ix1 < WID) ? 1.f : 0.f;
        half8v w00v = splat8((_Float16)((1.f - wy) * (1.f - wx) * m00));
        half8v w01v = splat8((_Float16)((1.f - wy) * wx * m01));
        half8v w10v = splat8((_Float16)(wy * (1.f - wx) * m10));
        half8v w11v = splat8((_Float16)(wy * wx * m11));

        bool fast = (iy0 >= ry0) && (iy1 <= ry0 + RB - 1) &&
                    (ix0 >= rx0) && (ix1 <= rx0 + WB - 1);

        if (__builtin_expect(fast, 1)) {
            int p00 = (iy0 - ry0) * WB + (ix0 - rx0);
            int p01 = p00 + 1, p10 = p00 + WB, p11 = p00 + WB + 1;
            int s00 = p00 & 7, s01 = p01 & 7, s10 = p10 & 7, s11 = p11 & 7;
#pragma unroll
            for (int m = 0; m < 4; m++) {
                int cs = m * 2 + h;
                half8v c00 = sm[p00 * 8 + (cs ^ s00)];
                half8v c01 = sm[p01 * 8 + (cs ^ s01)];
                half8v c10 = sm[p10 * 8 + (cs ^ s10)];
                half8v c11 = sm[p11 * 8 + (cs ^ s11)];
                half8v bf = c00 * w00v + c01 * w01v + c10 * w10v + c11 * w11v;
                acc0 = __builtin_amdgcn_mfma_f32_32x32x16_f16(a0[m], bf, acc0, 0, 0, 0);
                acc1 = __builtin_amdgcn_mfma_f32_32x32x16_f16(a1[m], bf, acc1, 0, 0, 0);
            }
        } else {
            int cy0 = min(max(iy0, 0), HH - 1), cy1 = min(max(iy1, 0), HH - 1);
            int cx0 = min(max(ix0, 0), WID - 1), cx1 = min(max(ix1, 0), WID - 1);
            size_t i00 = (size_t)(cy0 * WID + cx0) * 8, i01 = (size_t)(cy0 * WID + cx1) * 8;
            size_t i10 = (size_t)(cy1 * WID + cx0) * 8, i11 = (size_t)(cy1 * WID + cx1) * 8;
#pragma unroll
            for (int m = 0; m < 4; m++) {
                const _Float16* xq = xb + (size_t)(m * 2 + h) * HW * 8;
                half8v c00 = *(const half8v*)(xq + i00);
                half8v c01 = *(const half8v*)(xq + i01);
                half8v c10 = *(const half8v*)(xq + i10);
                half8v c11 = *(const half8v*)(xq + i11);
                half8v bf = c00 * w00v + c01 * w01v + c10 * w10v + c11 * w11v;
                acc0 = __builtin_amdgcn_mfma_f32_32x32x16_f16(a0[m], bf, acc0, 0, 0, 0);
                acc1 = __builtin_amdgcn_mfma_f32_32x32x16_f16(a1[m], bf, acc1, 0, 0, 0);
            }
        }

        offc = offn;
        kj++;
        if (kj == K) { kj = 0; ki++; }
    }

    // ---- epilogue: D: pos = l31, o = t*32 + (reg&3) + 8*(reg>>2) + 4*h ----
    int hwp = yt * WID + xt;
    _Float16* ob = outp + (size_t)b * HW * 64 + (size_t)hwp * 8 + 4 * h;
#pragma unroll
    for (int g = 0; g < 4; g++) {
        float4 bb0 = *(const float4*)&bias[g * 8 + 4 * h];
        half4v r0;
        r0[0] = (_Float16)(acc0[g * 4 + 0] + bb0.x);
        r0[1] = (_Float16)(acc0[g * 4 + 1] + bb0.y);
        r0[2] = (_Float16)(acc0[g * 4 + 2] + bb0.z);
        r0[3] = (_Float16)(acc0[g * 4 + 3] + bb0.w);
        *(half4v*)&ob[(size_t)g * HW * 8] = r0;
        float4 bb1 = *(const float4*)&bias[32 + g * 8 + 4 * h];
        half4v r1;
        r1[0] = (_Float16)(acc1[g * 4 + 0] + bb1.x);
        r1[1] = (_Float16)(acc1[g * 4 + 1] + bb1.y);
        r1[2] = (_Float16)(acc1[g * 4 + 2] + bb1.z);
        r1[3] = (_Float16)(acc1[g * 4 + 3] + bb1.w);
        *(half4v*)&ob[(size_t)(4 + g) * HW * 8] = r1;
    }
}

// ---------------------------------------------------------------------------
// k_soconv v3: = v2 with global_load_lds staging. Zero-fill semantics kept by
// divergent split: in-image lanes issue the DMA (wave-uniform LDS base, so
// exec-mask holes can't skew base+lane*16 addressing); out-of-image lanes
// ds_write zeros to their own (disjoint) slots. Both drained by the barrier.
// ---------------------------------------------------------------------------
template<int K, int PAD, int NTILE, int CO>
__global__ __launch_bounds__(256) void k_soconv(
    const _Float16* __restrict__ xin,
    const _Float16* __restrict__ wtb, const float* __restrict__ bias,
    float* __restrict__ outf)
{
    constexpr int KK = K * K;
    constexpr int KTAP = CO / 2;
    constexpr int HALO = PAD;
    constexpr int RB = 16 + 2 * HALO;
    constexpr int WB = 8  + 2 * HALO;
    constexpr int OP = NTILE * 32;

    __shared__ half8v sm[RB * WB * 8];

    int bi  = blockIdx.x;
    int b   = bi / 288;
    int tt  = bi % 288;
    int by0 = (tt / 24) * 16;
    int bx0 = (tt % 24) * 8;
    int ry0 = by0 - HALO;
    int rx0 = bx0 - HALO;

    const _Float16* xb = xin + (size_t)b * HW * 64;

    // ---- stage tile + halo via global_load_lds, zero-fill outside image ----
    {
        _Float16* smlin = (_Float16*)sm;
        constexpr int CH = RB * WB * 8;
        for (int i0 = 0; i0 < CH; i0 += 256) {
            int i    = i0 + (int)threadIdx.x;
            int wbse = i0 + ((int)threadIdx.x & 192);    // wave-uniform chunk base
            if (i < CH) {
                int pix = i >> 3;
                int ts  = i & 7;
                int pl  = ts ^ (pix & 7);
                int r   = pix / WB;
                int cc  = pix - r * WB;
                int yr  = ry0 + r;
                int xc  = rx0 + cc;
                bool ok = (yr >= 0 && yr < HH && xc >= 0 && xc < WID);
                if (ok) {
                    const _Float16* src = xb + ((size_t)pl * HW + (size_t)(yr * WID + xc)) * 8;
                    __builtin_amdgcn_global_load_lds(src, &smlin[(size_t)wbse * 8], 16, 0, 0);
                } else {
                    *(half8v*)&smlin[(size_t)i * 8] = splat8((_Float16)0.f);
                }
            }
        }
    }
    __syncthreads();

    int lane = threadIdx.x & 63;
    int wave = threadIdx.x >> 6;          // 0..3
    int l31  = lane & 31;
    int h    = lane >> 5;
    int prow = l31 >> 3;
    int pcol = l31 & 7;

    int yt = by0 + wave * 4 + prow;
    int xt = bx0 + pcol;
    int gp = b * HW + yt * WID + xt;

    const half8v* wbase = (const half8v*)wtb;

    f32x16 acc[NTILE];
#pragma unroll
    for (int tI = 0; tI < NTILE; tI++)
#pragma unroll
        for (int r = 0; r < 16; r++) acc[tI][r] = 0.f;

    int ki = 0, kj = 0;
    for (int k = 0; k < KK; k++) {
        int rr  = (yt + ki - PAD) - ry0;     // in [0, RB)
        int ccx = (xt + kj - PAD) - rx0;     // in [0, WB)
        int pix = rr * WB + ccx;
        int s   = pix & 7;

#pragma unroll
        for (int m = 0; m < 4; m++) {
            int cs = m * 2 + h;
            half8v bf = sm[pix * 8 + (cs ^ s)];
            const half8v* wp = wbase + ((size_t)k * 8 + cs) * OP;
#pragma unroll
            for (int tI = 0; tI < NTILE; tI++) {
                half8v a = wp[tI * 32 + l31];
                acc[tI] = __builtin_amdgcn_mfma_f32_32x32x16_f16(a, bf, acc[tI], 0, 0, 0);
            }
        }

        kj++;
        if (kj == K) { kj = 0; ki++; }
    }

    // ---- epilogue: tap-major float2 planes, o = tile*32 + i + 8g + 4h ----
#pragma unroll
    for (int tI = 0; tI < NTILE; tI++) {
#pragma unroll
        for (int g = 0; g < 4; g++) {
            int base = tI * 32 + 8 * g + 4 * h;
#pragma unroll
            for (int pr = 0; pr < 2; pr++) {
                int o  = base + 2 * pr;
                int t0 = o >> 1;
                if (t0 < KTAP) {
                    float2 r;
                    r.x = acc[tI][g * 4 + 2 * pr]     + bias[o];
                    r.y = acc[tI][g * 4 + 2 * pr + 1] + bias[o + 1];
                    *(float2*)&outf[((size_t)t0 * NPOS + gp) * 2] = r;
                }
            }
        }
    }
}

// ---------------------------------------------------------------------------
// K4 (MFMA): h = x1_final + x2; out = h @ w_out^T + b_out + x (NCHW fp32).
// ---------------------------------------------------------------------------
__global__ __launch_bounds__(256) void k_merge_mfma(
    const _Float16* __restrict__ x1f, const _Float16* __restrict__ x2,
    const float* __restrict__ xin, const _Float16* __restrict__ wt_out,
    const float* __restrict__ b_out, float* __restrict__ out)
{
    int p0  = blockIdx.x * 128;
    int b   = p0 / HW;
    int hwb = p0 % HW;

    int lane = threadIdx.x & 63;
    int wave = threadIdx.x >> 6;
    int l31  = lane & 31;
    int h    = lane >> 5;
    int pos  = hwb + wave * 32 + l31;

    const _Float16* a1 = x1f + (size_t)b * HW * 64 + (size_t)pos * 8;
    const _Float16* a2 = x2  + (size_t)b * HW * 64 + (size_t)pos * 8;

    half8v bf[4];
#pragma unroll
    for (int m = 0; m < 4; m++) {
        int cs = m * 2 + h;
        half8v u1 = *(const half8v*)&a1[(size_t)cs * HW * 8];
        half8v u2 = *(const half8v*)&a2[(size_t)cs * HW * 8];
        bf[m] = u1 + u2;
    }

    f32x16 acc[2];
#pragma unroll
    for (int tI = 0; tI < 2; tI++)
#pragma unroll
        for (int r = 0; r < 16; r++) acc[tI][r] = 0.f;

    const half8v* wbase = (const half8v*)wt_out;
#pragma unroll
    for (int m = 0; m < 4; m++) {
        int cs = m * 2 + h;
        const half8v* wp = wbase + (size_t)cs * 64;       // OP = 64
#pragma unroll
        for (int tI = 0; tI < 2; tI++) {
            half8v a = wp[tI * 32 + l31];
            acc[tI] = __builtin_amdgcn_mfma_f32_32x32x16_f16(a, bf[m], acc[tI], 0, 0, 0);
        }
    }

    size_t base = (size_t)b * CB * HW + pos;
#pragma unroll
    for (int tI = 0; tI < 2; tI++) {
#pragma unroll
        for (int gidx = 0; gidx < 4; gidx++) {
            int o0 = tI * 32 + gidx * 8 + 4 * h;
#pragma unroll
            for (int i = 0; i < 4; i++) {
                int o = o0 + i;
                out[base + (size_t)o * HW] =
                    acc[tI][gidx * 4 + i] + b_out[o] + xin[base + (size_t)o * HW];
            }
        }
    }
}

// ---------------------------------------------------------------------------
// Launch. Workspace: x1a/x1b/x2 plane fp16 (18.9 MB each), off tap-major
// float2 planes (59 MB), fp16 weights (~1.5 MB, fragment-major; wto1 OP=128;
// + wt_in 16KB, wt_out 8KB for the 1x1 convs).
// ---------------------------------------------------------------------------
extern "C" void kernel_launch(void* const* d_in, const int* in_sizes, int n_in,
                              void* d_out, int out_size, void* d_ws, size_t ws_size,
                              hipStream_t stream)
{
    const float* x     = (const float*)d_in[0];
    const float* ln_w  = (const float*)d_in[1];
    const float* ln_b  = (const float*)d_in[2];
    const float* w_in  = (const float*)d_in[3];
    const float* b_in  = (const float*)d_in[4];
    const float* w_out = (const float*)d_in[5];
    const float* b_out = (const float*)d_in[6];
    const float* dw1   = (const float*)d_in[7];
    const float* db1   = (const float*)d_in[8];
    const float* dw2   = (const float*)d_in[9];
    const float* db2   = (const float*)d_in[10];
    const float* dw3   = (const float*)d_in[11];
    const float* db3   = (const float*)d_in[12];
    const float* ow1   = (const float*)d_in[13];
    const float* ob1   = (const float*)d_in[14];
    const float* ow2   = (const float*)d_in[15];
    const float* ob2   = (const float*)d_in[16];
    const float* ow3   = (const float*)d_in[17];
    const float* ob3   = (const float*)d_in[18];

    _Float16* x1a = (_Float16*)d_ws;
    _Float16* x1b = x1a + (size_t)NPOS * 64;
    _Float16* x2  = x1b + (size_t)NPOS * 64;
    float* off = (float*)(x2 + (size_t)NPOS * 64);
    _Float16* wtd1 = (_Float16*)(off + (size_t)NPOS * 100);
    _Float16* wtd2 = wtd1 + 49 * 64 * 64;
    _Float16* wtd3 = wtd2 + 25 * 64 * 64;
    _Float16* wto1 = wtd3 +  9 * 64 * 64;
    _Float16* wto2 = wto1 + 25 * 128 * 64;   // OP=128
    _Float16* wto3 = wto2 + 25 * 64 * 64;
    _Float16* wtin = wto3 +  9 * 32 * 64;
    _Float16* wtou = wtin + 128 * 64;

    // weight prep (fp16, fragment-major [tap][cs][o][8ch]); 1x1 convs KK=1
    k_wth<49, 64,  64><<<784, 256, 0, stream>>>(dw1, wtd1);
    k_wth<25, 64,  64><<<400, 256, 0, stream>>>(dw2, wtd2);
    k_wth< 9, 64,  64><<<144, 256, 0, stream>>>(dw3, wtd3);
    k_wth<25, 98, 128><<<800, 256, 0, stream>>>(ow1, wto1);
    k_wth<25, 50,  64><<<400, 256, 0, stream>>>(ow2, wto2);
    k_wth< 9, 18,  32><<< 72, 256, 0, stream>>>(ow3, wto3);
    k_wth< 1, 128, 128><<<32, 256, 0, stream>>>(w_in, wtin);
    k_wth< 1, 64,  64><<<16, 256, 0, stream>>>(w_out, wtou);

    // LN + 1x1 conv (MFMA)
    k_lnconv_mfma<<<NPOS / 128, 256, 0, stream>>>(x, ln_w, ln_b, wtin, b_in, x1a, x2);

    // stage 1
    k_soconv<5, 2, 4, 98><<<1152, 256, 0, stream>>>(x1a, wto1, ob1, off);
    k_sconv<7, 3, 4><<<1152, 256, 0, stream>>>(x1a, off, wtd1, db1, x1b);
    // stage 2
    k_soconv<5, 2, 2, 50><<<1152, 256, 0, stream>>>(x1b, wto2, ob2, off);
    k_sconv<5, 2, 3><<<1152, 256, 0, stream>>>(x1b, off, wtd2, db2, x1a);
    // stage 3
    k_soconv<3, 1, 1, 18><<<1152, 256, 0, stream>>>(x1a, wto3, ob3, off);
    k_sconv<3, 1, 2><<<1152, 256, 0, stream>>>(x1a, off, wtd3, db3, x1b);

    // merge + 1x1 conv + residual (MFMA)
    k_merge_mfma<<<NPOS / 128, 256, 0, stream>>>(x1b, x2, x, wtou, b_out, (float*)d_out);
}

// Round 11
// 530.890 us; speedup vs baseline: 2.2609x; 1.0959x over previous
//
#include <hip/hip_runtime.h>

// Problem constants (B=4, C=64, H=W=192)
#define HH 192
#define WID 192
#define HW (HH*WID)          // 36864
#define CB 64
#define BB 4
#define NPOS (BB*HW)         // 147456

typedef __attribute__((ext_vector_type(8))) _Float16 half8v;
typedef __attribute__((ext_vector_type(4))) _Float16 half4v;
typedef __attribute__((ext_vector_type(4))) float f32x4;
typedef __attribute__((ext_vector_type(16))) float f32x16;

static __device__ inline half8v splat8(_Float16 x) {
    half8v v = {x, x, x, x, x, x, x, x};
    return v;
}

// x tensors: CHANNEL-PLANE fp16 layout x[b][plane=c>>3][hw][8ch] (16B/pos/plane).
// Offsets: TAP-MAJOR float2 planes off[k][global_pos][2] (NPOS float2 per plane).
// Weights: FRAGMENT-MAJOR fp16 wt[k][cs][o][8ch], cs = 8-channel chunk.
// Staging: __builtin_amdgcn_global_load_lds width=16, LINEAR LDS dest
// (wave-uniform base + lane*16), swizzle applied on the SOURCE address.

// ---------------------------------------------------------------------------
// Weight prep: w[o][c][ki][kj] fp32 (OIHW) -> wt[k][cs][o][j] fp16
// (fragment-major; o padded to OP; c = cs*8 + j). KK=1 handles 1x1 convs.
// ---------------------------------------------------------------------------
template<int KK, int CO, int OP>
__global__ void k_wth(const float* __restrict__ w, _Float16* __restrict__ wt)
{
    int idx = blockIdx.x * 256 + threadIdx.x;
    constexpr int TOT = KK * OP * 64;
    if (idx >= TOT) return;
    int k  = idx / (OP * 64);
    int r  = idx % (OP * 64);
    int cs = r / (OP * 8);
    int r2 = r % (OP * 8);
    int o  = r2 / 8;
    int j  = r2 % 8;
    int c  = cs * 8 + j;
    float v = (o < CO) ? w[((size_t)o * 64 + c) * KK + k] : 0.f;
    wt[idx] = (_Float16)v;
}

// ---------------------------------------------------------------------------
// K1 (MFMA): LayerNorm over C + 1x1 conv C->2C via 32x32x16 MFMA.
// Block = 128 positions, 4 waves x 32 pos; 2 lanes/position (h = lane>>5).
// ---------------------------------------------------------------------------
__global__ __launch_bounds__(256) void k_lnconv_mfma(
    const float* __restrict__ x, const float* __restrict__ g, const float* __restrict__ be,
    const _Float16* __restrict__ wt_in, const float* __restrict__ b_in,
    _Float16* __restrict__ x1, _Float16* __restrict__ x2)
{
    int p0  = blockIdx.x * 128;
    int b   = p0 / HW;
    int hwb = p0 % HW;

    int lane = threadIdx.x & 63;
    int wave = threadIdx.x >> 6;
    int l31  = lane & 31;
    int h    = lane >> 5;
    int pos  = hwb + wave * 32 + l31;

    const float* xp = x + (size_t)b * CB * HW + pos;

    float v[32];
    float sum = 0.f, sumsq = 0.f;
#pragma unroll
    for (int m = 0; m < 4; m++)
#pragma unroll
        for (int j = 0; j < 8; j++) {
            float t = xp[(size_t)(m * 16 + h * 8 + j) * HW];
            v[m * 8 + j] = t; sum += t; sumsq += t * t;
        }
    sum   += __shfl_xor(sum, 32);
    sumsq += __shfl_xor(sumsq, 32);
    float mu  = sum * (1.f / 64.f);
    float var = sumsq * (1.f / 64.f) - mu * mu;
    float inv = rsqrtf(var + 1e-5f);

    half8v bf[4];
#pragma unroll
    for (int m = 0; m < 4; m++)
#pragma unroll
        for (int j = 0; j < 8; j++) {
            int c = m * 16 + h * 8 + j;
            bf[m][j] = (_Float16)((v[m * 8 + j] - mu) * inv * g[c] + be[c]);
        }

    f32x16 acc[4];
#pragma unroll
    for (int tI = 0; tI < 4; tI++)
#pragma unroll
        for (int r = 0; r < 16; r++) acc[tI][r] = 0.f;

    const half8v* wbase = (const half8v*)wt_in;
#pragma unroll
    for (int m = 0; m < 4; m++) {
        int cs = m * 2 + h;
        const half8v* wp = wbase + (size_t)cs * 128;      // OP = 128
#pragma unroll
        for (int tI = 0; tI < 4; tI++) {
            half8v a = wp[tI * 32 + l31];
            acc[tI] = __builtin_amdgcn_mfma_f32_32x32x16_f16(a, bf[m], acc[tI], 0, 0, 0);
        }
    }

    _Float16* o1 = x1 + (size_t)b * HW * 64 + (size_t)pos * 8;
    _Float16* o2 = x2 + (size_t)b * HW * 64 + (size_t)pos * 8;
#pragma unroll
    for (int tI = 0; tI < 4; tI++) {
        _Float16* ob = (tI < 2) ? o1 : o2;
        int obase = (tI & 1) * 32;
#pragma unroll
        for (int gidx = 0; gidx < 4; gidx++) {
            int o = obase + gidx * 8 + 4 * h;
            float4 bb = *(const float4*)&b_in[tI * 32 + gidx * 8 + 4 * h];
            half4v r;
            r[0] = (_Float16)(acc[tI][gidx * 4 + 0] + bb.x);
            r[1] = (_Float16)(acc[tI][gidx * 4 + 1] + bb.y);
            r[2] = (_Float16)(acc[tI][gidx * 4 + 2] + bb.z);
            r[3] = (_Float16)(acc[tI][gidx * 4 + 3] + bb.w);
            *(half4v*)&ob[(size_t)(o >> 3) * HW * 8 + (o & 7)] = r;
        }
    }
}

// ---------------------------------------------------------------------------
// k_sconv v8 (unchanged from round 10): LDS-staged deform conv, 32x32x16 MFMA,
// fragment-major weights, global_load_lds staging (swizzle on source addr).
// ---------------------------------------------------------------------------
template<int K, int PAD, int HALO>
__global__ __launch_bounds__(256) void k_sconv(
    const _Float16* __restrict__ xin, const float* __restrict__ offp,
    const _Float16* __restrict__ wtb, const float* __restrict__ bias,
    _Float16* __restrict__ outp)
{
    constexpr int KK = K * K;
    constexpr int RB = 16 + 2 * HALO;     // staged rows
    constexpr int WB = 8  + 2 * HALO;     // staged cols

    __shared__ half8v sm[RB * WB * 8];    // 16B slot per (pixel, plane)

    int bi  = blockIdx.x;
    int b   = bi / 288;                   // 288 = 12 row-tiles * 24 col-tiles
    int tt  = bi % 288;
    int by0 = (tt / 24) * 16;
    int bx0 = (tt % 24) * 8;
    int ry0 = by0 - HALO;
    int rx0 = bx0 - HALO;

    const _Float16* xb  = xin + (size_t)b * HW * 64;

    // ---- stage tile + halo via global_load_lds (edge-clamped source) ----
    {
        _Float16* smlin = (_Float16*)sm;
        constexpr int CH = RB * WB * 8;
        for (int i0 = 0; i0 < CH; i0 += 256) {
            int i     = i0 + (int)threadIdx.x;
            int wbse  = i0 + ((int)threadIdx.x & 192);   // wave-uniform chunk base
            if (i < CH) {
                int pix = i >> 3;
                int ts  = i & 7;
                int pl  = ts ^ (pix & 7);
                int r   = pix / WB;
                int cc  = pix - r * WB;
                int yr  = min(max(ry0 + r,  0), HH - 1);
                int xc  = min(max(rx0 + cc, 0), WID - 1);
                const _Float16* src = xb + ((size_t)pl * HW + (size_t)(yr * WID + xc)) * 8;
                __builtin_amdgcn_global_load_lds(src, &smlin[(size_t)wbse * 8], 16, 0, 0);
            }
        }
    }
    __syncthreads();

    int t    = threadIdx.x;
    int lane = t & 63;
    int wave = t >> 6;                    // 0..3 -> rows wave*4..wave*4+3
    int l31  = lane & 31;                 // position index within wave tile
    int h    = lane >> 5;                 // K-half (channel chunk parity)
    int prow = l31 >> 3;                  // 0..3
    int pcol = l31 & 7;                   // 0..7

    int yt = by0 + wave * 4 + prow;
    int xt = bx0 + pcol;
    int gp = b * HW + yt * WID + xt;

    const half8v* wbase = (const half8v*)wtb;

    f32x16 acc0 = {0.f,0.f,0.f,0.f,0.f,0.f,0.f,0.f,0.f,0.f,0.f,0.f,0.f,0.f,0.f,0.f};
    f32x16 acc1 = {0.f,0.f,0.f,0.f,0.f,0.f,0.f,0.f,0.f,0.f,0.f,0.f,0.f,0.f,0.f,0.f};

    const float2* offj = (const float2*)offp + gp;
    float2 offc = offj[0];

    int ki = 0, kj = 0;
    for (int k = 0; k < KK; k++) {
        // prefetch next tap's offset (one tap of cover, v1-proven)
        float2 offn = offj[(size_t)(k + 1) * NPOS];

        // A-frags, fragment-major: wt[k][cs][o] -> lane-contiguous 16B
        half8v a0[4], a1[4];
#pragma unroll
        for (int m = 0; m < 4; m++) {
            int cs = m * 2 + h;
            const half8v* wp = wbase + ((size_t)k * 8 + cs) * 64;   // OP = 64
            a0[m] = wp[l31];
            a1[m] = wp[32 + l31];
        }

        // per-lane sample coordinates (ONE position per lane-pair)
        float py = (float)(yt + ki - PAD) + offc.x;
        float px = (float)(xt + kj - PAD) + offc.y;
        float fy = floorf(py), fx = floorf(px);
        float wy = py - fy, wx = px - fx;
        int iy0 = (int)fy, ix0 = (int)fx;
        int iy1 = iy0 + 1, ix1 = ix0 + 1;
        float m00 = (iy0 >= 0 && iy0 < HH && ix0 >= 0 && ix0 < WID) ? 1.f : 0.f;
        float m01 = (iy0 >= 0 && iy0 < HH && ix1 >= 0 && ix1 < WID) ? 1.f : 0.f;
        float m10 = (iy1 >= 0 && iy1 < HH && ix0 >= 0 && ix0 < WID) ? 1.f : 0.f;
        float m11 = (iy1 >= 0 && iy1 < HH && ix1 >= 0 && ix1 < WID) ? 1.f : 0.f;
        half8v w00v = splat8((_Float16)((1.f - wy) * (1.f - wx) * m00));
        half8v w01v = splat8((_Float16)((1.f - wy) * wx * m01));
        half8v w10v = splat8((_Float16)(wy * (1.f - wx) * m10));
        half8v w11v = splat8((_Float16)(wy * wx * m11));

        bool fast = (iy0 >= ry0) && (iy1 <= ry0 + RB - 1) &&
                    (ix0 >= rx0) && (ix1 <= rx0 + WB - 1);

        if (__builtin_expect(fast, 1)) {
            int p00 = (iy0 - ry0) * WB + (ix0 - rx0);
            int p01 = p00 + 1, p10 = p00 + WB, p11 = p00 + WB + 1;
            int s00 = p00 & 7, s01 = p01 & 7, s10 = p10 & 7, s11 = p11 & 7;
#pragma unroll
            for (int m = 0; m < 4; m++) {
                int cs = m * 2 + h;
                half8v c00 = sm[p00 * 8 + (cs ^ s00)];
                half8v c01 = sm[p01 * 8 + (cs ^ s01)];
                half8v c10 = sm[p10 * 8 + (cs ^ s10)];
                half8v c11 = sm[p11 * 8 + (cs ^ s11)];
                half8v bf = c00 * w00v + c01 * w01v + c10 * w10v + c11 * w11v;
                acc0 = __builtin_amdgcn_mfma_f32_32x32x16_f16(a0[m], bf, acc0, 0, 0, 0);
                acc1 = __builtin_amdgcn_mfma_f32_32x32x16_f16(a1[m], bf, acc1, 0, 0, 0);
            }
        } else {
            int cy0 = min(max(iy0, 0), HH - 1), cy1 = min(max(iy1, 0), HH - 1);
            int cx0 = min(max(ix0, 0), WID - 1), cx1 = min(max(ix1, 0), WID - 1);
            size_t i00 = (size_t)(cy0 * WID + cx0) * 8, i01 = (size_t)(cy0 * WID + cx1) * 8;
            size_t i10 = (size_t)(cy1 * WID + cx0) * 8, i11 = (size_t)(cy1 * WID + cx1) * 8;
#pragma unroll
            for (int m = 0; m < 4; m++) {
                const _Float16* xq = xb + (size_t)(m * 2 + h) * HW * 8;
                half8v c00 = *(const half8v*)(xq + i00);
                half8v c01 = *(const half8v*)(xq + i01);
                half8v c10 = *(const half8v*)(xq + i10);
                half8v c11 = *(const half8v*)(xq + i11);
                half8v bf = c00 * w00v + c01 * w01v + c10 * w10v + c11 * w11v;
                acc0 = __builtin_amdgcn_mfma_f32_32x32x16_f16(a0[m], bf, acc0, 0, 0, 0);
                acc1 = __builtin_amdgcn_mfma_f32_32x32x16_f16(a1[m], bf, acc1, 0, 0, 0);
            }
        }

        offc = offn;
        kj++;
        if (kj == K) { kj = 0; ki++; }
    }

    // ---- epilogue: D: pos = l31, o = t*32 + (reg&3) + 8*(reg>>2) + 4*h ----
    int hwp = yt * WID + xt;
    _Float16* ob = outp + (size_t)b * HW * 64 + (size_t)hwp * 8 + 4 * h;
#pragma unroll
    for (int g = 0; g < 4; g++) {
        float4 bb0 = *(const float4*)&bias[g * 8 + 4 * h];
        half4v r0;
        r0[0] = (_Float16)(acc0[g * 4 + 0] + bb0.x);
        r0[1] = (_Float16)(acc0[g * 4 + 1] + bb0.y);
        r0[2] = (_Float16)(acc0[g * 4 + 2] + bb0.z);
        r0[3] = (_Float16)(acc0[g * 4 + 3] + bb0.w);
        *(half4v*)&ob[(size_t)g * HW * 8] = r0;
        float4 bb1 = *(const float4*)&bias[32 + g * 8 + 4 * h];
        half4v r1;
        r1[0] = (_Float16)(acc1[g * 4 + 0] + bb1.x);
        r1[1] = (_Float16)(acc1[g * 4 + 1] + bb1.y);
        r1[2] = (_Float16)(acc1[g * 4 + 2] + bb1.z);
        r1[3] = (_Float16)(acc1[g * 4 + 3] + bb1.w);
        *(half4v*)&ob[(size_t)(4 + g) * HW * 8] = r1;
    }
}

// ---------------------------------------------------------------------------
// k_soconv v4 (round 11): CHANNEL-SPLIT waves. Round-10 PMC: 141us, MfmaUtil
// 17, VALU 7, HBM 8% -- latency-bound on GLOBAL WEIGHT LOADS: each of the 4
// waves redundantly loaded all CT*4 weight frags per tap (load:MFMA = 1:1).
// v4: wave w = (ct = w%CT, pp = w/CT) owns channel-tile ct for CT position-
// groups (g = pp*CT + q). Per tap per wave: 4 weight loads (was 4*CT) +
// 4*CT LDS bf reads + 4*CT MFMA -> global-load:MFMA ratio improves CT-fold,
// block weight traffic / 4. CT=1 degenerates to the previous proven form.
// Same fragment layout, swizzle, staging, tap-major epilogue.
// ---------------------------------------------------------------------------
template<int K, int PAD, int CT, int CO>
__global__ __launch_bounds__(256) void k_soconv(
    const _Float16* __restrict__ xin,
    const _Float16* __restrict__ wtb, const float* __restrict__ bias,
    float* __restrict__ outf)
{
    constexpr int KK = K * K;
    constexpr int KTAP = CO / 2;
    constexpr int HALO = PAD;
    constexpr int RB = 16 + 2 * HALO;
    constexpr int WB = 8  + 2 * HALO;
    constexpr int OP = CT * 32;

    __shared__ half8v sm[RB * WB * 8];

    int bi  = blockIdx.x;
    int b   = bi / 288;
    int tt  = bi % 288;
    int by0 = (tt / 24) * 16;
    int bx0 = (tt % 24) * 8;
    int ry0 = by0 - HALO;
    int rx0 = bx0 - HALO;

    const _Float16* xb = xin + (size_t)b * HW * 64;

    // ---- stage tile + halo via global_load_lds, zero-fill outside image ----
    {
        _Float16* smlin = (_Float16*)sm;
        constexpr int CH = RB * WB * 8;
        for (int i0 = 0; i0 < CH; i0 += 256) {
            int i    = i0 + (int)threadIdx.x;
            int wbse = i0 + ((int)threadIdx.x & 192);    // wave-uniform chunk base
            if (i < CH) {
                int pix = i >> 3;
                int ts  = i & 7;
                int pl  = ts ^ (pix & 7);
                int r   = pix / WB;
                int cc  = pix - r * WB;
                int yr  = ry0 + r;
                int xc  = rx0 + cc;
                bool ok = (yr >= 0 && yr < HH && xc >= 0 && xc < WID);
                if (ok) {
                    const _Float16* src = xb + ((size_t)pl * HW + (size_t)(yr * WID + xc)) * 8;
                    __builtin_amdgcn_global_load_lds(src, &smlin[(size_t)wbse * 8], 16, 0, 0);
                } else {
                    *(half8v*)&smlin[(size_t)i * 8] = splat8((_Float16)0.f);
                }
            }
        }
    }
    __syncthreads();

    int lane = threadIdx.x & 63;
    int wave = threadIdx.x >> 6;          // 0..3
    int l31  = lane & 31;
    int h    = lane >> 5;
    int prow = l31 >> 3;
    int pcol = l31 & 7;

    int ct = wave % CT;                   // channel tile this wave owns
    int pp = wave / CT;                   // position partition

    int xt = bx0 + pcol;
    int yt[CT], gp[CT];
#pragma unroll
    for (int q = 0; q < CT; q++) {
        int g = pp * CT + q;              // position group 0..3
        yt[q] = by0 + g * 4 + prow;
        gp[q] = b * HW + yt[q] * WID + xt;
    }

    const half8v* wbase = (const half8v*)wtb;

    f32x16 acc[CT];
#pragma unroll
    for (int q = 0; q < CT; q++)
#pragma unroll
        for (int r = 0; r < 16; r++) acc[q][r] = 0.f;

    int ki = 0, kj = 0;
    for (int k = 0; k < KK; k++) {
        int ccx = (xt + kj - PAD) - rx0;     // in [0, WB)
        int pix[CT];
#pragma unroll
        for (int q = 0; q < CT; q++)
            pix[q] = ((yt[q] + ki - PAD) - ry0) * WB + ccx;

#pragma unroll
        for (int m = 0; m < 4; m++) {
            int cs = m * 2 + h;
            const half8v* wp = wbase + ((size_t)k * 8 + cs) * OP;
            half8v a = wp[ct * 32 + l31];
#pragma unroll
            for (int q = 0; q < CT; q++) {
                half8v bf = sm[pix[q] * 8 + (cs ^ (pix[q] & 7))];
                acc[q] = __builtin_amdgcn_mfma_f32_32x32x16_f16(a, bf, acc[q], 0, 0, 0);
            }
        }

        kj++;
        if (kj == K) { kj = 0; ki++; }
    }

    // ---- epilogue: tap-major float2 planes, o = ct*32 + gi*8 + 4h + 2pr ----
#pragma unroll
    for (int q = 0; q < CT; q++) {
#pragma unroll
        for (int gi = 0; gi < 4; gi++) {
            int obase = ct * 32 + 8 * gi + 4 * h;
#pragma unroll
            for (int pr = 0; pr < 2; pr++) {
                int o  = obase + 2 * pr;
                int t0 = o >> 1;
                if (t0 < KTAP) {
                    float2 r;
                    r.x = acc[q][gi * 4 + 2 * pr]     + bias[o];
                    r.y = acc[q][gi * 4 + 2 * pr + 1] + bias[o + 1];
                    *(float2*)&outf[((size_t)t0 * NPOS + gp[q]) * 2] = r;
                }
            }
        }
    }
}

// ---------------------------------------------------------------------------
// K4 (MFMA): h = x1_final + x2; out = h @ w_out^T + b_out + x (NCHW fp32).
// ---------------------------------------------------------------------------
__global__ __launch_bounds__(256) void k_merge_mfma(
    const _Float16* __restrict__ x1f, const _Float16* __restrict__ x2,
    const float* __restrict__ xin, const _Float16* __restrict__ wt_out,
    const float* __restrict__ b_out, float* __restrict__ out)
{
    int p0  = blockIdx.x * 128;
    int b   = p0 / HW;
    int hwb = p0 % HW;

    int lane = threadIdx.x & 63;
    int wave = threadIdx.x >> 6;
    int l31  = lane & 31;
    int h    = lane >> 5;
    int pos  = hwb + wave * 32 + l31;

    const _Float16* a1 = x1f + (size_t)b * HW * 64 + (size_t)pos * 8;
    const _Float16* a2 = x2  + (size_t)b * HW * 64 + (size_t)pos * 8;

    half8v bf[4];
#pragma unroll
    for (int m = 0; m < 4; m++) {
        int cs = m * 2 + h;
        half8v u1 = *(const half8v*)&a1[(size_t)cs * HW * 8];
        half8v u2 = *(const half8v*)&a2[(size_t)cs * HW * 8];
        bf[m] = u1 + u2;
    }

    f32x16 acc[2];
#pragma unroll
    for (int tI = 0; tI < 2; tI++)
#pragma unroll
        for (int r = 0; r < 16; r++) acc[tI][r] = 0.f;

    const half8v* wbase = (const half8v*)wt_out;
#pragma unroll
    for (int m = 0; m < 4; m++) {
        int cs = m * 2 + h;
        const half8v* wp = wbase + (size_t)cs * 64;       // OP = 64
#pragma unroll
        for (int tI = 0; tI < 2; tI++) {
            half8v a = wp[tI * 32 + l31];
            acc[tI] = __builtin_amdgcn_mfma_f32_32x32x16_f16(a, bf[m], acc[tI], 0, 0, 0);
        }
    }

    size_t base = (size_t)b * CB * HW + pos;
#pragma unroll
    for (int tI = 0; tI < 2; tI++) {
#pragma unroll
        for (int gidx = 0; gidx < 4; gidx++) {
            int o0 = tI * 32 + gidx * 8 + 4 * h;
#pragma unroll
            for (int i = 0; i < 4; i++) {
                int o = o0 + i;
                out[base + (size_t)o * HW] =
                    acc[tI][gidx * 4 + i] + b_out[o] + xin[base + (size_t)o * HW];
            }
        }
    }
}

// ---------------------------------------------------------------------------
// Launch. Workspace: x1a/x1b/x2 plane fp16 (18.9 MB each), off tap-major
// float2 planes (59 MB), fp16 weights (~1.5 MB, fragment-major; wto1 OP=128;
// + wt_in 16KB, wt_out 8KB for the 1x1 convs).
// ---------------------------------------------------------------------------
extern "C" void kernel_launch(void* const* d_in, const int* in_sizes, int n_in,
                              void* d_out, int out_size, void* d_ws, size_t ws_size,
                              hipStream_t stream)
{
    const float* x     = (const float*)d_in[0];
    const float* ln_w  = (const float*)d_in[1];
    const float* ln_b  = (const float*)d_in[2];
    const float* w_in  = (const float*)d_in[3];
    const float* b_in  = (const float*)d_in[4];
    const float* w_out = (const float*)d_in[5];
    const float* b_out = (const float*)d_in[6];
    const float* dw1   = (const float*)d_in[7];
    const float* db1   = (const float*)d_in[8];
    const float* dw2   = (const float*)d_in[9];
    const float* db2   = (const float*)d_in[10];
    const float* dw3   = (const float*)d_in[11];
    const float* db3   = (const float*)d_in[12];
    const float* ow1   = (const float*)d_in[13];
    const float* ob1   = (const float*)d_in[14];
    const float* ow2   = (const float*)d_in[15];
    const float* ob2   = (const float*)d_in[16];
    const float* ow3   = (const float*)d_in[17];
    const float* ob3   = (const float*)d_in[18];

    _Float16* x1a = (_Float16*)d_ws;
    _Float16* x1b = x1a + (size_t)NPOS * 64;
    _Float16* x2  = x1b + (size_t)NPOS * 64;
    float* off = (float*)(x2 + (size_t)NPOS * 64);
    _Float16* wtd1 = (_Float16*)(off + (size_t)NPOS * 100);
    _Float16* wtd2 = wtd1 + 49 * 64 * 64;
    _Float16* wtd3 = wtd2 + 25 * 64 * 64;
    _Float16* wto1 = wtd3 +  9 * 64 * 64;
    _Float16* wto2 = wto1 + 25 * 128 * 64;   // OP=128
    _Float16* wto3 = wto2 + 25 * 64 * 64;
    _Float16* wtin = wto3 +  9 * 32 * 64;
    _Float16* wtou = wtin + 128 * 64;

    // weight prep (fp16, fragment-major [tap][cs][o][8ch]); 1x1 convs KK=1
    k_wth<49, 64,  64><<<784, 256, 0, stream>>>(dw1, wtd1);
    k_wth<25, 64,  64><<<400, 256, 0, stream>>>(dw2, wtd2);
    k_wth< 9, 64,  64><<<144, 256, 0, stream>>>(dw3, wtd3);
    k_wth<25, 98, 128><<<800, 256, 0, stream>>>(ow1, wto1);
    k_wth<25, 50,  64><<<400, 256, 0, stream>>>(ow2, wto2);
    k_wth< 9, 18,  32><<< 72, 256, 0, stream>>>(ow3, wto3);
    k_wth< 1, 128, 128><<<32, 256, 0, stream>>>(w_in, wtin);
    k_wth< 1, 64,  64><<<16, 256, 0, stream>>>(w_out, wtou);

    // LN + 1x1 conv (MFMA)
    k_lnconv_mfma<<<NPOS / 128, 256, 0, stream>>>(x, ln_w, ln_b, wtin, b_in, x1a, x2);

    // stage 1
    k_soconv<5, 2, 4, 98><<<1152, 256, 0, stream>>>(x1a, wto1, ob1, off);
    k_sconv<7, 3, 4><<<1152, 256, 0, stream>>>(x1a, off, wtd1, db1, x1b);
    // stage 2
    k_soconv<5, 2, 2, 50><<<1152, 256, 0, stream>>>(x1b, wto2, ob2, off);
    k_sconv<5, 2, 3><<<1152, 256, 0, stream>>>(x1b, off, wtd2, db2, x1a);
    // stage 3
    k_soconv<3, 1, 1, 18><<<1152, 256, 0, stream>>>(x1a, wto3, ob3, off);
    k_sconv<3, 1, 2><<<1152, 256, 0, stream>>>(x1a, off, wtd3, db3, x1b);

    // merge + 1x1 conv + residual (MFMA)
    k_merge_mfma<<<NPOS / 128, 256, 0, stream>>>(x1b, x2, x, wtou, b_out, (float*)d_out);
}

// Round 12
// 489.105 us; speedup vs baseline: 2.4541x; 1.0854x over previous
//
#include <hip/hip_runtime.h>

// Problem constants (B=4, C=64, H=W=192)
#define HH 192
#define WID 192
#define HW (HH*WID)          // 36864
#define CB 64
#define BB 4
#define NPOS (BB*HW)         // 147456

typedef __attribute__((ext_vector_type(8))) _Float16 half8v;
typedef __attribute__((ext_vector_type(4))) _Float16 half4v;
typedef __attribute__((ext_vector_type(2))) _Float16 half2v;
typedef __attribute__((ext_vector_type(4))) float f32x4;
typedef __attribute__((ext_vector_type(16))) float f32x16;

static __device__ inline half8v splat8(_Float16 x) {
    half8v v = {x, x, x, x, x, x, x, x};
    return v;
}

// x tensors: CHANNEL-PLANE fp16 layout x[b][plane=c>>3][hw][8ch] (16B/pos/plane).
// Weights: FRAGMENT-MAJOR fp16 wt[k][cs][o][8ch], cs = 8-channel chunk.
// Round 12: offset conv + deform conv FUSED per stage (k_fconv). Offsets never
// touch global memory -- phase A writes fp16 half2 per (tap, position) into an
// LDS region; phase B (deform) reads them back with a broadcast ds_read.
// Kills: 59MB off buffer traffic (~115MB/stage-1 round trip), duplicate tile
// staging, 3 dispatches. Tile staged once, ZERO-FILL (conv semantics; deform's
// masked corners don't care).

// ---------------------------------------------------------------------------
// Weight prep: w[o][c][ki][kj] fp32 (OIHW) -> wt[k][cs][o][j] fp16
// (fragment-major; o padded to OP; c = cs*8 + j). KK=1 handles 1x1 convs.
// ---------------------------------------------------------------------------
template<int KK, int CO, int OP>
__global__ void k_wth(const float* __restrict__ w, _Float16* __restrict__ wt)
{
    int idx = blockIdx.x * 256 + threadIdx.x;
    constexpr int TOT = KK * OP * 64;
    if (idx >= TOT) return;
    int k  = idx / (OP * 64);
    int r  = idx % (OP * 64);
    int cs = r / (OP * 8);
    int r2 = r % (OP * 8);
    int o  = r2 / 8;
    int j  = r2 % 8;
    int c  = cs * 8 + j;
    float v = (o < CO) ? w[((size_t)o * 64 + c) * KK + k] : 0.f;
    wt[idx] = (_Float16)v;
}

// ---------------------------------------------------------------------------
// K1 (MFMA): LayerNorm over C + 1x1 conv C->2C via 32x32x16 MFMA.
// ---------------------------------------------------------------------------
__global__ __launch_bounds__(256) void k_lnconv_mfma(
    const float* __restrict__ x, const float* __restrict__ g, const float* __restrict__ be,
    const _Float16* __restrict__ wt_in, const float* __restrict__ b_in,
    _Float16* __restrict__ x1, _Float16* __restrict__ x2)
{
    int p0  = blockIdx.x * 128;
    int b   = p0 / HW;
    int hwb = p0 % HW;

    int lane = threadIdx.x & 63;
    int wave = threadIdx.x >> 6;
    int l31  = lane & 31;
    int h    = lane >> 5;
    int pos  = hwb + wave * 32 + l31;

    const float* xp = x + (size_t)b * CB * HW + pos;

    float v[32];
    float sum = 0.f, sumsq = 0.f;
#pragma unroll
    for (int m = 0; m < 4; m++)
#pragma unroll
        for (int j = 0; j < 8; j++) {
            float t = xp[(size_t)(m * 16 + h * 8 + j) * HW];
            v[m * 8 + j] = t; sum += t; sumsq += t * t;
        }
    sum   += __shfl_xor(sum, 32);
    sumsq += __shfl_xor(sumsq, 32);
    float mu  = sum * (1.f / 64.f);
    float var = sumsq * (1.f / 64.f) - mu * mu;
    float inv = rsqrtf(var + 1e-5f);

    half8v bf[4];
#pragma unroll
    for (int m = 0; m < 4; m++)
#pragma unroll
        for (int j = 0; j < 8; j++) {
            int c = m * 16 + h * 8 + j;
            bf[m][j] = (_Float16)((v[m * 8 + j] - mu) * inv * g[c] + be[c]);
        }

    f32x16 acc[4];
#pragma unroll
    for (int tI = 0; tI < 4; tI++)
#pragma unroll
        for (int r = 0; r < 16; r++) acc[tI][r] = 0.f;

    const half8v* wbase = (const half8v*)wt_in;
#pragma unroll
    for (int m = 0; m < 4; m++) {
        int cs = m * 2 + h;
        const half8v* wp = wbase + (size_t)cs * 128;      // OP = 128
#pragma unroll
        for (int tI = 0; tI < 4; tI++) {
            half8v a = wp[tI * 32 + l31];
            acc[tI] = __builtin_amdgcn_mfma_f32_32x32x16_f16(a, bf[m], acc[tI], 0, 0, 0);
        }
    }

    _Float16* o1 = x1 + (size_t)b * HW * 64 + (size_t)pos * 8;
    _Float16* o2 = x2 + (size_t)b * HW * 64 + (size_t)pos * 8;
#pragma unroll
    for (int tI = 0; tI < 4; tI++) {
        _Float16* ob = (tI < 2) ? o1 : o2;
        int obase = (tI & 1) * 32;
#pragma unroll
        for (int gidx = 0; gidx < 4; gidx++) {
            int o = obase + gidx * 8 + 4 * h;
            float4 bb = *(const float4*)&b_in[tI * 32 + gidx * 8 + 4 * h];
            half4v r;
            r[0] = (_Float16)(acc[tI][gidx * 4 + 0] + bb.x);
            r[1] = (_Float16)(acc[tI][gidx * 4 + 1] + bb.y);
            r[2] = (_Float16)(acc[tI][gidx * 4 + 2] + bb.z);
            r[3] = (_Float16)(acc[tI][gidx * 4 + 3] + bb.w);
            *(half4v*)&ob[(size_t)(o >> 3) * HW * 8 + (o & 7)] = r;
        }
    }
}

// ---------------------------------------------------------------------------
// k_fconv: FUSED offset-conv (phase A, = round-11 channel-split soconv) +
// deform-conv (phase B, = round-10 sconv). One zero-fill staged tile, two
// barriers, offsets exchanged via LDS as fp16 half2 (4B per tap*position).
// KD/PAD/HALO: deform kernel; KO/PADO: offset conv (PADO <= HALO); CT:
// channel tiles of the offset conv (OP = CT*32 >= 2*KD*KD).
// ---------------------------------------------------------------------------
template<int KD, int PAD, int HALO, int KO, int PADO, int CT>
__global__ __launch_bounds__(256) void k_fconv(
    const _Float16* __restrict__ xin,
    const _Float16* __restrict__ wto, const float* __restrict__ obias,
    const _Float16* __restrict__ wtd, const float* __restrict__ dbias,
    _Float16* __restrict__ outp)
{
    constexpr int KKD = KD * KD;          // deform taps = offset channel pairs
    constexpr int KKO = KO * KO;          // offset-conv taps
    constexpr int RB = 16 + 2 * HALO;
    constexpr int WB = 8  + 2 * HALO;
    constexpr int OP = CT * 32;

    __shared__ half8v sm[RB * WB * 8];    // staged tile (16B slot/(pixel,plane))
    __shared__ unsigned int offs[KKD * 128];  // fp16 half2 offset per (tap,pos)

    int bi  = blockIdx.x;
    int b   = bi / 288;                   // 288 = 12 row-tiles * 24 col-tiles
    int tt  = bi % 288;
    int by0 = (tt / 24) * 16;
    int bx0 = (tt % 24) * 8;
    int ry0 = by0 - HALO;
    int rx0 = bx0 - HALO;

    const _Float16* xb = xin + (size_t)b * HW * 64;

    // ---- stage tile + halo via global_load_lds, ZERO-FILL outside image ----
    {
        _Float16* smlin = (_Float16*)sm;
        constexpr int CH = RB * WB * 8;
        for (int i0 = 0; i0 < CH; i0 += 256) {
            int i    = i0 + (int)threadIdx.x;
            int wbse = i0 + ((int)threadIdx.x & 192);    // wave-uniform chunk base
            if (i < CH) {
                int pix = i >> 3;
                int ts  = i & 7;
                int pl  = ts ^ (pix & 7);
                int r   = pix / WB;
                int cc  = pix - r * WB;
                int yr  = ry0 + r;
                int xc  = rx0 + cc;
                bool ok = (yr >= 0 && yr < HH && xc >= 0 && xc < WID);
                if (ok) {
                    const _Float16* src = xb + ((size_t)pl * HW + (size_t)(yr * WID + xc)) * 8;
                    __builtin_amdgcn_global_load_lds(src, &smlin[(size_t)wbse * 8], 16, 0, 0);
                } else {
                    *(half8v*)&smlin[(size_t)i * 8] = splat8((_Float16)0.f);
                }
            }
        }
    }
    __syncthreads();

    int lane = threadIdx.x & 63;
    int wave = threadIdx.x >> 6;          // 0..3
    int l31  = lane & 31;
    int h    = lane >> 5;
    int prow = l31 >> 3;                  // 0..3
    int pcol = l31 & 7;                   // 0..7
    int xt   = bx0 + pcol;

    // =========================== phase A: offset conv ======================
    {
        int ct = wave % CT;               // channel tile this wave owns
        int pp = wave / CT;               // position partition

        int ytA[CT], pA[CT];
#pragma unroll
        for (int q = 0; q < CT; q++) {
            int g = pp * CT + q;          // position group 0..3
            ytA[q] = by0 + g * 4 + prow;
            pA[q]  = g * 32 + l31;        // block-local position index
        }

        const half8v* wbase = (const half8v*)wto;

        f32x16 accO[CT];
#pragma unroll
        for (int q = 0; q < CT; q++)
#pragma unroll
            for (int r = 0; r < 16; r++) accO[q][r] = 0.f;

        int ki = 0, kj = 0;
        for (int k = 0; k < KKO; k++) {
            int ccx = (xt + kj - PADO) - rx0;
            int pixA[CT];
#pragma unroll
            for (int q = 0; q < CT; q++)
                pixA[q] = ((ytA[q] + ki - PADO) - ry0) * WB + ccx;

#pragma unroll
            for (int m = 0; m < 4; m++) {
                int cs = m * 2 + h;
                const half8v* wp = wbase + ((size_t)k * 8 + cs) * OP;
                half8v a = wp[ct * 32 + l31];
#pragma unroll
                for (int q = 0; q < CT; q++) {
                    half8v bf = sm[pixA[q] * 8 + (cs ^ (pixA[q] & 7))];
                    accO[q] = __builtin_amdgcn_mfma_f32_32x32x16_f16(a, bf, accO[q], 0, 0, 0);
                }
            }

            kj++;
            if (kj == KO) { kj = 0; ki++; }
        }

        // epilogue A -> LDS offsets: o = ct*32 + 8gi + 4h + 2pr; tap = o/2
#pragma unroll
        for (int q = 0; q < CT; q++) {
#pragma unroll
            for (int gi = 0; gi < 4; gi++) {
                int obase = ct * 32 + 8 * gi + 4 * h;
#pragma unroll
                for (int pr = 0; pr < 2; pr++) {
                    int o  = obase + 2 * pr;
                    int kt = o >> 1;
                    if (kt < KKD) {
                        half2v hv;
                        hv[0] = (_Float16)(accO[q][gi * 4 + 2 * pr]     + obias[o]);
                        hv[1] = (_Float16)(accO[q][gi * 4 + 2 * pr + 1] + obias[o + 1]);
                        *(half2v*)&offs[kt * 128 + pA[q]] = hv;
                    }
                }
            }
        }
    }
    __syncthreads();

    // =========================== phase B: deform conv ======================
    int yt   = by0 + wave * 4 + prow;
    int p128 = wave * 32 + l31;

    const half8v* wbase = (const half8v*)wtd;

    f32x16 acc0 = {0.f,0.f,0.f,0.f,0.f,0.f,0.f,0.f,0.f,0.f,0.f,0.f,0.f,0.f,0.f,0.f};
    f32x16 acc1 = {0.f,0.f,0.f,0.f,0.f,0.f,0.f,0.f,0.f,0.f,0.f,0.f,0.f,0.f,0.f,0.f};

    int ki = 0, kj = 0;
    for (int k = 0; k < KKD; k++) {
        // offset for this tap & position: LDS broadcast read (lane pairs share)
        half2v ov = *(const half2v*)&offs[k * 128 + p128];
        float ox = (float)ov[0];
        float oy = (float)ov[1];

        // A-frags, fragment-major: wt[k][cs][o] -> lane-contiguous 16B
        half8v a0[4], a1[4];
#pragma unroll
        for (int m = 0; m < 4; m++) {
            int cs = m * 2 + h;
            const half8v* wp = wbase + ((size_t)k * 8 + cs) * 64;   // OP = 64
            a0[m] = wp[l31];
            a1[m] = wp[32 + l31];
        }

        float py = (float)(yt + ki - PAD) + ox;
        float px = (float)(xt + kj - PAD) + oy;
        float fy = floorf(py), fx = floorf(px);
        float wy = py - fy, wx = px - fx;
        int iy0 = (int)fy, ix0 = (int)fx;
        int iy1 = iy0 + 1, ix1 = ix0 + 1;
        float m00 = (iy0 >= 0 && iy0 < HH && ix0 >= 0 && ix0 < WID) ? 1.f : 0.f;
        float m01 = (iy0 >= 0 && iy0 < HH && ix1 >= 0 && ix1 < WID) ? 1.f : 0.f;
        float m10 = (iy1 >= 0 && iy1 < HH && ix0 >= 0 && ix0 < WID) ? 1.f : 0.f;
        float m11 = (iy1 >= 0 && iy1 < HH && ix1 >= 0 && ix1 < WID) ? 1.f : 0.f;
        half8v w00v = splat8((_Float16)((1.f - wy) * (1.f - wx) * m00));
        half8v w01v = splat8((_Float16)((1.f - wy) * wx * m01));
        half8v w10v = splat8((_Float16)(wy * (1.f - wx) * m10));
        half8v w11v = splat8((_Float16)(wy * wx * m11));

        bool fast = (iy0 >= ry0) && (iy1 <= ry0 + RB - 1) &&
                    (ix0 >= rx0) && (ix1 <= rx0 + WB - 1);

        if (__builtin_expect(fast, 1)) {
            int p00 = (iy0 - ry0) * WB + (ix0 - rx0);
            int p01 = p00 + 1, p10 = p00 + WB, p11 = p00 + WB + 1;
            int s00 = p00 & 7, s01 = p01 & 7, s10 = p10 & 7, s11 = p11 & 7;
#pragma unroll
            for (int m = 0; m < 4; m++) {
                int cs = m * 2 + h;
                half8v c00 = sm[p00 * 8 + (cs ^ s00)];
                half8v c01 = sm[p01 * 8 + (cs ^ s01)];
                half8v c10 = sm[p10 * 8 + (cs ^ s10)];
                half8v c11 = sm[p11 * 8 + (cs ^ s11)];
                half8v bf = c00 * w00v + c01 * w01v + c10 * w10v + c11 * w11v;
                acc0 = __builtin_amdgcn_mfma_f32_32x32x16_f16(a0[m], bf, acc0, 0, 0, 0);
                acc1 = __builtin_amdgcn_mfma_f32_32x32x16_f16(a1[m], bf, acc1, 0, 0, 0);
            }
        } else {
            int cy0 = min(max(iy0, 0), HH - 1), cy1 = min(max(iy1, 0), HH - 1);
            int cx0 = min(max(ix0, 0), WID - 1), cx1 = min(max(ix1, 0), WID - 1);
            size_t i00 = (size_t)(cy0 * WID + cx0) * 8, i01 = (size_t)(cy0 * WID + cx1) * 8;
            size_t i10 = (size_t)(cy1 * WID + cx0) * 8, i11 = (size_t)(cy1 * WID + cx1) * 8;
#pragma unroll
            for (int m = 0; m < 4; m++) {
                const _Float16* xq = xb + (size_t)(m * 2 + h) * HW * 8;
                half8v c00 = *(const half8v*)(xq + i00);
                half8v c01 = *(const half8v*)(xq + i01);
                half8v c10 = *(const half8v*)(xq + i10);
                half8v c11 = *(const half8v*)(xq + i11);
                half8v bf = c00 * w00v + c01 * w01v + c10 * w10v + c11 * w11v;
                acc0 = __builtin_amdgcn_mfma_f32_32x32x16_f16(a0[m], bf, acc0, 0, 0, 0);
                acc1 = __builtin_amdgcn_mfma_f32_32x32x16_f16(a1[m], bf, acc1, 0, 0, 0);
            }
        }

        kj++;
        if (kj == KD) { kj = 0; ki++; }
    }

    // ---- epilogue B: D: pos = l31, o = t*32 + (reg&3) + 8*(reg>>2) + 4h ----
    int hwp = yt * WID + xt;
    _Float16* ob = outp + (size_t)b * HW * 64 + (size_t)hwp * 8 + 4 * h;
#pragma unroll
    for (int g = 0; g < 4; g++) {
        float4 bb0 = *(const float4*)&dbias[g * 8 + 4 * h];
        half4v r0;
        r0[0] = (_Float16)(acc0[g * 4 + 0] + bb0.x);
        r0[1] = (_Float16)(acc0[g * 4 + 1] + bb0.y);
        r0[2] = (_Float16)(acc0[g * 4 + 2] + bb0.z);
        r0[3] = (_Float16)(acc0[g * 4 + 3] + bb0.w);
        *(half4v*)&ob[(size_t)g * HW * 8] = r0;
        float4 bb1 = *(const float4*)&dbias[32 + g * 8 + 4 * h];
        half4v r1;
        r1[0] = (_Float16)(acc1[g * 4 + 0] + bb1.x);
        r1[1] = (_Float16)(acc1[g * 4 + 1] + bb1.y);
        r1[2] = (_Float16)(acc1[g * 4 + 2] + bb1.z);
        r1[3] = (_Float16)(acc1[g * 4 + 3] + bb1.w);
        *(half4v*)&ob[(size_t)(4 + g) * HW * 8] = r1;
    }
}

// ---------------------------------------------------------------------------
// K4 (MFMA): h = x1_final + x2; out = h @ w_out^T + b_out + x (NCHW fp32).
// ---------------------------------------------------------------------------
__global__ __launch_bounds__(256) void k_merge_mfma(
    const _Float16* __restrict__ x1f, const _Float16* __restrict__ x2,
    const float* __restrict__ xin, const _Float16* __restrict__ wt_out,
    const float* __restrict__ b_out, float* __restrict__ out)
{
    int p0  = blockIdx.x * 128;
    int b   = p0 / HW;
    int hwb = p0 % HW;

    int lane = threadIdx.x & 63;
    int wave = threadIdx.x >> 6;
    int l31  = lane & 31;
    int h    = lane >> 5;
    int pos  = hwb + wave * 32 + l31;

    const _Float16* a1 = x1f + (size_t)b * HW * 64 + (size_t)pos * 8;
    const _Float16* a2 = x2  + (size_t)b * HW * 64 + (size_t)pos * 8;

    half8v bf[4];
#pragma unroll
    for (int m = 0; m < 4; m++) {
        int cs = m * 2 + h;
        half8v u1 = *(const half8v*)&a1[(size_t)cs * HW * 8];
        half8v u2 = *(const half8v*)&a2[(size_t)cs * HW * 8];
        bf[m] = u1 + u2;
    }

    f32x16 acc[2];
#pragma unroll
    for (int tI = 0; tI < 2; tI++)
#pragma unroll
        for (int r = 0; r < 16; r++) acc[tI][r] = 0.f;

    const half8v* wbase = (const half8v*)wt_out;
#pragma unroll
    for (int m = 0; m < 4; m++) {
        int cs = m * 2 + h;
        const half8v* wp = wbase + (size_t)cs * 64;       // OP = 64
#pragma unroll
        for (int tI = 0; tI < 2; tI++) {
            half8v a = wp[tI * 32 + l31];
            acc[tI] = __builtin_amdgcn_mfma_f32_32x32x16_f16(a, bf[m], acc[tI], 0, 0, 0);
        }
    }

    size_t base = (size_t)b * CB * HW + pos;
#pragma unroll
    for (int tI = 0; tI < 2; tI++) {
#pragma unroll
        for (int gidx = 0; gidx < 4; gidx++) {
            int o0 = tI * 32 + gidx * 8 + 4 * h;
#pragma unroll
            for (int i = 0; i < 4; i++) {
                int o = o0 + i;
                out[base + (size_t)o * HW] =
                    acc[tI][gidx * 4 + i] + b_out[o] + xin[base + (size_t)o * HW];
            }
        }
    }
}

// ---------------------------------------------------------------------------
// Launch. Workspace layout unchanged (off region now unused). Weights ~1.5 MB
// fragment-major; wto1 OP=128; wt_in 16KB, wt_out 8KB.
// ---------------------------------------------------------------------------
extern "C" void kernel_launch(void* const* d_in, const int* in_sizes, int n_in,
                              void* d_out, int out_size, void* d_ws, size_t ws_size,
                              hipStream_t stream)
{
    const float* x     = (const float*)d_in[0];
    const float* ln_w  = (const float*)d_in[1];
    const float* ln_b  = (const float*)d_in[2];
    const float* w_in  = (const float*)d_in[3];
    const float* b_in  = (const float*)d_in[4];
    const float* w_out = (const float*)d_in[5];
    const float* b_out = (const float*)d_in[6];
    const float* dw1   = (const float*)d_in[7];
    const float* db1   = (const float*)d_in[8];
    const float* dw2   = (const float*)d_in[9];
    const float* db2   = (const float*)d_in[10];
    const float* dw3   = (const float*)d_in[11];
    const float* db3   = (const float*)d_in[12];
    const float* ow1   = (const float*)d_in[13];
    const float* ob1   = (const float*)d_in[14];
    const float* ow2   = (const float*)d_in[15];
    const float* ob2   = (const float*)d_in[16];
    const float* ow3   = (const float*)d_in[17];
    const float* ob3   = (const float*)d_in[18];

    _Float16* x1a = (_Float16*)d_ws;
    _Float16* x1b = x1a + (size_t)NPOS * 64;
    _Float16* x2  = x1b + (size_t)NPOS * 64;
    float* off = (float*)(x2 + (size_t)NPOS * 64);       // unused (kept for layout)
    _Float16* wtd1 = (_Float16*)(off + (size_t)NPOS * 100);
    _Float16* wtd2 = wtd1 + 49 * 64 * 64;
    _Float16* wtd3 = wtd2 + 25 * 64 * 64;
    _Float16* wto1 = wtd3 +  9 * 64 * 64;
    _Float16* wto2 = wto1 + 25 * 128 * 64;   // OP=128
    _Float16* wto3 = wto2 + 25 * 64 * 64;
    _Float16* wtin = wto3 +  9 * 32 * 64;
    _Float16* wtou = wtin + 128 * 64;

    // weight prep (fp16, fragment-major [tap][cs][o][8ch]); 1x1 convs KK=1
    k_wth<49, 64,  64><<<784, 256, 0, stream>>>(dw1, wtd1);
    k_wth<25, 64,  64><<<400, 256, 0, stream>>>(dw2, wtd2);
    k_wth< 9, 64,  64><<<144, 256, 0, stream>>>(dw3, wtd3);
    k_wth<25, 98, 128><<<800, 256, 0, stream>>>(ow1, wto1);
    k_wth<25, 50,  64><<<400, 256, 0, stream>>>(ow2, wto2);
    k_wth< 9, 18,  32><<< 72, 256, 0, stream>>>(ow3, wto3);
    k_wth< 1, 128, 128><<<32, 256, 0, stream>>>(w_in, wtin);
    k_wth< 1, 64,  64><<<16, 256, 0, stream>>>(w_out, wtou);

    // LN + 1x1 conv (MFMA)
    k_lnconv_mfma<<<NPOS / 128, 256, 0, stream>>>(x, ln_w, ln_b, wtin, b_in, x1a, x2);

    // fused offset+deform per stage (KD,PAD,HALO, KO,PADO, CT)
    k_fconv<7, 3, 4, 5, 2, 4><<<1152, 256, 0, stream>>>(x1a, wto1, ob1, wtd1, db1, x1b);
    k_fconv<5, 2, 3, 5, 2, 2><<<1152, 256, 0, stream>>>(x1b, wto2, ob2, wtd2, db2, x1a);
    k_fconv<3, 1, 2, 3, 1, 1><<<1152, 256, 0, stream>>>(x1a, wto3, ob3, wtd3, db3, x1b);

    // merge + 1x1 conv + residual (MFMA)
    k_merge_mfma<<<NPOS / 128, 256, 0, stream>>>(x1b, x2, x, wtou, b_out, (float*)d_out);
}

// Round 13
// 483.237 us; speedup vs baseline: 2.4839x; 1.0121x over previous
//
#include <hip/hip_runtime.h>

// Problem constants (B=4, C=64, H=W=192)
#define HH 192
#define WID 192
#define HW (HH*WID)          // 36864
#define CB 64
#define BB 4
#define NPOS (BB*HW)         // 147456

typedef __attribute__((ext_vector_type(8))) _Float16 half8v;
typedef __attribute__((ext_vector_type(4))) _Float16 half4v;
typedef __attribute__((ext_vector_type(2))) _Float16 half2v;
typedef __attribute__((ext_vector_type(4))) float f32x4;
typedef __attribute__((ext_vector_type(16))) float f32x16;

static __device__ inline half8v splat8(_Float16 x) {
    half8v v = {x, x, x, x, x, x, x, x};
    return v;
}

// x tensors: CHANNEL-PLANE fp16 layout x[b][plane=c>>3][hw][8ch] (16B/pos/plane).
// Weights: FRAGMENT-MAJOR fp16 wt[k][cs][o][8ch], cs = 8-channel chunk.
// k_fconv (round 13): 512 threads / 8 waves per 16x8 tile, SAME LDS footprint
// as round 12 (74.2/52.2/34.6 KB) -> 2-4 blocks/CU = 16-32 waves/CU (round-12
// PMC: 2 waves/SIMD was the binding constraint -- MfmaUtil 25 / VALU 37 / LDS
// ~33%, none saturated). Phase A work items (CT x 4 pos-groups) spread over
// 8 waves; phase B taps split across wave-groups with an LDS partial-sum
// reduction in the then-dead sm region.

// ---------------------------------------------------------------------------
// Weight prep: w[o][c][ki][kj] fp32 (OIHW) -> wt[k][cs][o][j] fp16
// (fragment-major; o padded to OP; c = cs*8 + j). KK=1 handles 1x1 convs.
// ---------------------------------------------------------------------------
template<int KK, int CO, int OP>
__global__ void k_wth(const float* __restrict__ w, _Float16* __restrict__ wt)
{
    int idx = blockIdx.x * 256 + threadIdx.x;
    constexpr int TOT = KK * OP * 64;
    if (idx >= TOT) return;
    int k  = idx / (OP * 64);
    int r  = idx % (OP * 64);
    int cs = r / (OP * 8);
    int r2 = r % (OP * 8);
    int o  = r2 / 8;
    int j  = r2 % 8;
    int c  = cs * 8 + j;
    float v = (o < CO) ? w[((size_t)o * 64 + c) * KK + k] : 0.f;
    wt[idx] = (_Float16)v;
}

// ---------------------------------------------------------------------------
// K1 (MFMA): LayerNorm over C + 1x1 conv C->2C via 32x32x16 MFMA.
// ---------------------------------------------------------------------------
__global__ __launch_bounds__(256) void k_lnconv_mfma(
    const float* __restrict__ x, const float* __restrict__ g, const float* __restrict__ be,
    const _Float16* __restrict__ wt_in, const float* __restrict__ b_in,
    _Float16* __restrict__ x1, _Float16* __restrict__ x2)
{
    int p0  = blockIdx.x * 128;
    int b   = p0 / HW;
    int hwb = p0 % HW;

    int lane = threadIdx.x & 63;
    int wave = threadIdx.x >> 6;
    int l31  = lane & 31;
    int h    = lane >> 5;
    int pos  = hwb + wave * 32 + l31;

    const float* xp = x + (size_t)b * CB * HW + pos;

    float v[32];
    float sum = 0.f, sumsq = 0.f;
#pragma unroll
    for (int m = 0; m < 4; m++)
#pragma unroll
        for (int j = 0; j < 8; j++) {
            float t = xp[(size_t)(m * 16 + h * 8 + j) * HW];
            v[m * 8 + j] = t; sum += t; sumsq += t * t;
        }
    sum   += __shfl_xor(sum, 32);
    sumsq += __shfl_xor(sumsq, 32);
    float mu  = sum * (1.f / 64.f);
    float var = sumsq * (1.f / 64.f) - mu * mu;
    float inv = rsqrtf(var + 1e-5f);

    half8v bf[4];
#pragma unroll
    for (int m = 0; m < 4; m++)
#pragma unroll
        for (int j = 0; j < 8; j++) {
            int c = m * 16 + h * 8 + j;
            bf[m][j] = (_Float16)((v[m * 8 + j] - mu) * inv * g[c] + be[c]);
        }

    f32x16 acc[4];
#pragma unroll
    for (int tI = 0; tI < 4; tI++)
#pragma unroll
        for (int r = 0; r < 16; r++) acc[tI][r] = 0.f;

    const half8v* wbase = (const half8v*)wt_in;
#pragma unroll
    for (int m = 0; m < 4; m++) {
        int cs = m * 2 + h;
        const half8v* wp = wbase + (size_t)cs * 128;      // OP = 128
#pragma unroll
        for (int tI = 0; tI < 4; tI++) {
            half8v a = wp[tI * 32 + l31];
            acc[tI] = __builtin_amdgcn_mfma_f32_32x32x16_f16(a, bf[m], acc[tI], 0, 0, 0);
        }
    }

    _Float16* o1 = x1 + (size_t)b * HW * 64 + (size_t)pos * 8;
    _Float16* o2 = x2 + (size_t)b * HW * 64 + (size_t)pos * 8;
#pragma unroll
    for (int tI = 0; tI < 4; tI++) {
        _Float16* ob = (tI < 2) ? o1 : o2;
        int obase = (tI & 1) * 32;
#pragma unroll
        for (int gidx = 0; gidx < 4; gidx++) {
            int o = obase + gidx * 8 + 4 * h;
            float4 bb = *(const float4*)&b_in[tI * 32 + gidx * 8 + 4 * h];
            half4v r;
            r[0] = (_Float16)(acc[tI][gidx * 4 + 0] + bb.x);
            r[1] = (_Float16)(acc[tI][gidx * 4 + 1] + bb.y);
            r[2] = (_Float16)(acc[tI][gidx * 4 + 2] + bb.z);
            r[3] = (_Float16)(acc[tI][gidx * 4 + 3] + bb.w);
            *(half4v*)&ob[(size_t)(o >> 3) * HW * 8 + (o & 7)] = r;
        }
    }
}

// ---------------------------------------------------------------------------
// k_fconv v2: FUSED offset+deform conv, 512 threads / 8 waves per 16x8 tile.
// Phase A: items (ct, g) over 8 waves (ct = wave%CT, g = (wave/CT)*IPW + q).
// Phase B: wave-group (wave>>2) computes tap range [T0, T1); group 1 dumps
// partial acc into the dead sm region; group 0 reduces + epilogue.
// ---------------------------------------------------------------------------
template<int KD, int PAD, int HALO, int KO, int PADO, int CT>
__global__ __launch_bounds__(512) void k_fconv(
    const _Float16* __restrict__ xin,
    const _Float16* __restrict__ wto, const float* __restrict__ obias,
    const _Float16* __restrict__ wtd, const float* __restrict__ dbias,
    _Float16* __restrict__ outp)
{
    constexpr int KKD = KD * KD;          // deform taps = offset channel pairs
    constexpr int KKO = KO * KO;          // offset-conv taps
    constexpr int RB = 16 + 2 * HALO;
    constexpr int WB = 8  + 2 * HALO;
    constexpr int OP = CT * 32;
    constexpr int IPW = (CT * 4 + 7) / 8; // phase-A items per wave (guarded)
    constexpr int THALF = (KKD + 1) / 2;  // phase-B tap split point

    __shared__ half8v sm[RB * WB * 8];    // staged tile; later: partial-acc buf
    __shared__ unsigned int offs[KKD * 128];  // fp16 half2 offset per (tap,pos)

    int bi  = blockIdx.x;
    int b   = bi / 288;                   // 288 = 12 row-tiles * 24 col-tiles
    int tt  = bi % 288;
    int by0 = (tt / 24) * 16;
    int bx0 = (tt % 24) * 8;
    int ry0 = by0 - HALO;
    int rx0 = bx0 - HALO;

    const _Float16* xb = xin + (size_t)b * HW * 64;

    // ---- stage tile + halo via global_load_lds, ZERO-FILL outside image ----
    {
        _Float16* smlin = (_Float16*)sm;
        constexpr int CH = RB * WB * 8;
        for (int i0 = 0; i0 < CH; i0 += 512) {
            int i    = i0 + (int)threadIdx.x;
            int wbse = i0 + ((int)threadIdx.x & 448);    // wave-uniform chunk base
            if (i < CH) {
                int pix = i >> 3;
                int ts  = i & 7;
                int pl  = ts ^ (pix & 7);
                int r   = pix / WB;
                int cc  = pix - r * WB;
                int yr  = ry0 + r;
                int xc  = rx0 + cc;
                bool ok = (yr >= 0 && yr < HH && xc >= 0 && xc < WID);
                if (ok) {
                    const _Float16* src = xb + ((size_t)pl * HW + (size_t)(yr * WID + xc)) * 8;
                    __builtin_amdgcn_global_load_lds(src, &smlin[(size_t)wbse * 8], 16, 0, 0);
                } else {
                    *(half8v*)&smlin[(size_t)i * 8] = splat8((_Float16)0.f);
                }
            }
        }
    }
    __syncthreads();

    int lane = threadIdx.x & 63;
    int wave = threadIdx.x >> 6;          // 0..7
    int l31  = lane & 31;
    int h    = lane >> 5;
    int prow = l31 >> 3;                  // 0..3
    int pcol = l31 & 7;                   // 0..7
    int xt   = bx0 + pcol;

    // =========================== phase A: offset conv ======================
    {
        int ct    = wave % CT;            // channel tile this wave owns
        int pslot = wave / CT;            // position-slot index

        int ytA[IPW], pA[IPW];
        bool gok[IPW];
#pragma unroll
        for (int q = 0; q < IPW; q++) {
            int g = pslot * IPW + q;      // position group
            gok[q] = (g < 4);
            int gc = gok[q] ? g : 0;
            ytA[q] = by0 + gc * 4 + prow;
            pA[q]  = gc * 32 + l31;
        }

        const half8v* wbase = (const half8v*)wto;

        f32x16 accO[IPW];
#pragma unroll
        for (int q = 0; q < IPW; q++)
#pragma unroll
            for (int r = 0; r < 16; r++) accO[q][r] = 0.f;

        int ki = 0, kj = 0;
        for (int k = 0; k < KKO; k++) {
            int ccx = (xt + kj - PADO) - rx0;
            int pixA[IPW];
#pragma unroll
            for (int q = 0; q < IPW; q++)
                pixA[q] = ((ytA[q] + ki - PADO) - ry0) * WB + ccx;

#pragma unroll
            for (int m = 0; m < 4; m++) {
                int cs = m * 2 + h;
                const half8v* wp = wbase + ((size_t)k * 8 + cs) * OP;
                half8v a = wp[ct * 32 + l31];
#pragma unroll
                for (int q = 0; q < IPW; q++) {
                    half8v bf = sm[pixA[q] * 8 + (cs ^ (pixA[q] & 7))];
                    accO[q] = __builtin_amdgcn_mfma_f32_32x32x16_f16(a, bf, accO[q], 0, 0, 0);
                }
            }

            kj++;
            if (kj == KO) { kj = 0; ki++; }
        }

        // epilogue A -> LDS offsets: o = ct*32 + 8gi + 4h + 2pr; tap = o/2
#pragma unroll
        for (int q = 0; q < IPW; q++) {
            if (gok[q]) {
#pragma unroll
                for (int gi = 0; gi < 4; gi++) {
                    int obase = ct * 32 + 8 * gi + 4 * h;
#pragma unroll
                    for (int pr = 0; pr < 2; pr++) {
                        int o  = obase + 2 * pr;
                        int kt = o >> 1;
                        if (kt < KKD) {
                            half2v hv;
                            hv[0] = (_Float16)(accO[q][gi * 4 + 2 * pr]     + obias[o]);
                            hv[1] = (_Float16)(accO[q][gi * 4 + 2 * pr + 1] + obias[o + 1]);
                            *(half2v*)&offs[kt * 128 + pA[q]] = hv;
                        }
                    }
                }
            }
        }
    }
    __syncthreads();

    // =========================== phase B: deform conv ======================
    int w4   = wave & 3;
    int grp  = wave >> 2;                 // tap group: 0 -> [0,THALF), 1 -> [THALF,KKD)
    int yt   = by0 + w4 * 4 + prow;
    int p128 = w4 * 32 + l31;

    const half8v* wbase = (const half8v*)wtd;

    f32x16 acc0 = {0.f,0.f,0.f,0.f,0.f,0.f,0.f,0.f,0.f,0.f,0.f,0.f,0.f,0.f,0.f,0.f};
    f32x16 acc1 = {0.f,0.f,0.f,0.f,0.f,0.f,0.f,0.f,0.f,0.f,0.f,0.f,0.f,0.f,0.f,0.f};

    int T0 = grp ? THALF : 0;
    int T1 = grp ? KKD : THALF;
    int ki = T0 / KD, kj = T0 % KD;
    for (int k = T0; k < T1; k++) {
        // offset for this tap & position: LDS broadcast read (lane pairs share)
        half2v ov = *(const half2v*)&offs[k * 128 + p128];
        float ox = (float)ov[0];
        float oy = (float)ov[1];

        // A-frags, fragment-major: wt[k][cs][o] -> lane-contiguous 16B
        half8v a0[4], a1[4];
#pragma unroll
        for (int m = 0; m < 4; m++) {
            int cs = m * 2 + h;
            const half8v* wp = wbase + ((size_t)k * 8 + cs) * 64;   // OP = 64
            a0[m] = wp[l31];
            a1[m] = wp[32 + l31];
        }

        float py = (float)(yt + ki - PAD) + ox;
        float px = (float)(xt + kj - PAD) + oy;
        float fy = floorf(py), fx = floorf(px);
        float wy = py - fy, wx = px - fx;
        int iy0 = (int)fy, ix0 = (int)fx;
        int iy1 = iy0 + 1, ix1 = ix0 + 1;
        float m00 = (iy0 >= 0 && iy0 < HH && ix0 >= 0 && ix0 < WID) ? 1.f : 0.f;
        float m01 = (iy0 >= 0 && iy0 < HH && ix1 >= 0 && ix1 < WID) ? 1.f : 0.f;
        float m10 = (iy1 >= 0 && iy1 < HH && ix0 >= 0 && ix0 < WID) ? 1.f : 0.f;
        float m11 = (iy1 >= 0 && iy1 < HH && ix1 >= 0 && ix1 < WID) ? 1.f : 0.f;
        half8v w00v = splat8((_Float16)((1.f - wy) * (1.f - wx) * m00));
        half8v w01v = splat8((_Float16)((1.f - wy) * wx * m01));
        half8v w10v = splat8((_Float16)(wy * (1.f - wx) * m10));
        half8v w11v = splat8((_Float16)(wy * wx * m11));

        bool fast = (iy0 >= ry0) && (iy1 <= ry0 + RB - 1) &&
                    (ix0 >= rx0) && (ix1 <= rx0 + WB - 1);

        if (__builtin_expect(fast, 1)) {
            int p00 = (iy0 - ry0) * WB + (ix0 - rx0);
            int p01 = p00 + 1, p10 = p00 + WB, p11 = p00 + WB + 1;
            int s00 = p00 & 7, s01 = p01 & 7, s10 = p10 & 7, s11 = p11 & 7;
#pragma unroll
            for (int m = 0; m < 4; m++) {
                int cs = m * 2 + h;
                half8v c00 = sm[p00 * 8 + (cs ^ s00)];
                half8v c01 = sm[p01 * 8 + (cs ^ s01)];
                half8v c10 = sm[p10 * 8 + (cs ^ s10)];
                half8v c11 = sm[p11 * 8 + (cs ^ s11)];
                half8v bf = c00 * w00v + c01 * w01v + c10 * w10v + c11 * w11v;
                acc0 = __builtin_amdgcn_mfma_f32_32x32x16_f16(a0[m], bf, acc0, 0, 0, 0);
                acc1 = __builtin_amdgcn_mfma_f32_32x32x16_f16(a1[m], bf, acc1, 0, 0, 0);
            }
        } else {
            int cy0 = min(max(iy0, 0), HH - 1), cy1 = min(max(iy1, 0), HH - 1);
            int cx0 = min(max(ix0, 0), WID - 1), cx1 = min(max(ix1, 0), WID - 1);
            size_t i00 = (size_t)(cy0 * WID + cx0) * 8, i01 = (size_t)(cy0 * WID + cx1) * 8;
            size_t i10 = (size_t)(cy1 * WID + cx0) * 8, i11 = (size_t)(cy1 * WID + cx1) * 8;
#pragma unroll
            for (int m = 0; m < 4; m++) {
                const _Float16* xq = xb + (size_t)(m * 2 + h) * HW * 8;
                half8v c00 = *(const half8v*)(xq + i00);
                half8v c01 = *(const half8v*)(xq + i01);
                half8v c10 = *(const half8v*)(xq + i10);
                half8v c11 = *(const half8v*)(xq + i11);
                half8v bf = c00 * w00v + c01 * w01v + c10 * w10v + c11 * w11v;
                acc0 = __builtin_amdgcn_mfma_f32_32x32x16_f16(a0[m], bf, acc0, 0, 0, 0);
                acc1 = __builtin_amdgcn_mfma_f32_32x32x16_f16(a1[m], bf, acc1, 0, 0, 0);
            }
        }

        kj++;
        if (kj == KD) { kj = 0; ki++; }
    }

    // ---- cross-group reduction: group 1 -> LDS (sm dead), group 0 adds ----
    __syncthreads();                      // all phase-B sm reads complete
    float* red = (float*)sm;              // 256 lanes * 32 floats = 32 KB
    if (grp == 1) {
        float* dst = red + ((size_t)(w4 * 64 + lane)) * 32;
#pragma unroll
        for (int r = 0; r < 16; r++) { dst[r] = acc0[r]; dst[16 + r] = acc1[r]; }
    }
    __syncthreads();
    if (grp == 0) {
        const float* src = red + ((size_t)(w4 * 64 + lane)) * 32;
#pragma unroll
        for (int r = 0; r < 16; r++) { acc0[r] += src[r]; acc1[r] += src[16 + r]; }

        // ---- epilogue B: D: pos = l31, o = t*32 + (r&3) + 8*(r>>2) + 4h ----
        int hwp = yt * WID + xt;
        _Float16* ob = outp + (size_t)b * HW * 64 + (size_t)hwp * 8 + 4 * h;
#pragma unroll
        for (int g = 0; g < 4; g++) {
            float4 bb0 = *(const float4*)&dbias[g * 8 + 4 * h];
            half4v r0;
            r0[0] = (_Float16)(acc0[g * 4 + 0] + bb0.x);
            r0[1] = (_Float16)(acc0[g * 4 + 1] + bb0.y);
            r0[2] = (_Float16)(acc0[g * 4 + 2] + bb0.z);
            r0[3] = (_Float16)(acc0[g * 4 + 3] + bb0.w);
            *(half4v*)&ob[(size_t)g * HW * 8] = r0;
            float4 bb1 = *(const float4*)&dbias[32 + g * 8 + 4 * h];
            half4v r1;
            r1[0] = (_Float16)(acc1[g * 4 + 0] + bb1.x);
            r1[1] = (_Float16)(acc1[g * 4 + 1] + bb1.y);
            r1[2] = (_Float16)(acc1[g * 4 + 2] + bb1.z);
            r1[3] = (_Float16)(acc1[g * 4 + 3] + bb1.w);
            *(half4v*)&ob[(size_t)(4 + g) * HW * 8] = r1;
        }
    }
}

// ---------------------------------------------------------------------------
// K4 (MFMA): h = x1_final + x2; out = h @ w_out^T + b_out + x (NCHW fp32).
// ---------------------------------------------------------------------------
__global__ __launch_bounds__(256) void k_merge_mfma(
    const _Float16* __restrict__ x1f, const _Float16* __restrict__ x2,
    const float* __restrict__ xin, const _Float16* __restrict__ wt_out,
    const float* __restrict__ b_out, float* __restrict__ out)
{
    int p0  = blockIdx.x * 128;
    int b   = p0 / HW;
    int hwb = p0 % HW;

    int lane = threadIdx.x & 63;
    int wave = threadIdx.x >> 6;
    int l31  = lane & 31;
    int h    = lane >> 5;
    int pos  = hwb + wave * 32 + l31;

    const _Float16* a1 = x1f + (size_t)b * HW * 64 + (size_t)pos * 8;
    const _Float16* a2 = x2  + (size_t)b * HW * 64 + (size_t)pos * 8;

    half8v bf[4];
#pragma unroll
    for (int m = 0; m < 4; m++) {
        int cs = m * 2 + h;
        half8v u1 = *(const half8v*)&a1[(size_t)cs * HW * 8];
        half8v u2 = *(const half8v*)&a2[(size_t)cs * HW * 8];
        bf[m] = u1 + u2;
    }

    f32x16 acc[2];
#pragma unroll
    for (int tI = 0; tI < 2; tI++)
#pragma unroll
        for (int r = 0; r < 16; r++) acc[tI][r] = 0.f;

    const half8v* wbase = (const half8v*)wt_out;
#pragma unroll
    for (int m = 0; m < 4; m++) {
        int cs = m * 2 + h;
        const half8v* wp = wbase + (size_t)cs * 64;       // OP = 64
#pragma unroll
        for (int tI = 0; tI < 2; tI++) {
            half8v a = wp[tI * 32 + l31];
            acc[tI] = __builtin_amdgcn_mfma_f32_32x32x16_f16(a, bf[m], acc[tI], 0, 0, 0);
        }
    }

    size_t base = (size_t)b * CB * HW + pos;
#pragma unroll
    for (int tI = 0; tI < 2; tI++) {
#pragma unroll
        for (int gidx = 0; gidx < 4; gidx++) {
            int o0 = tI * 32 + gidx * 8 + 4 * h;
#pragma unroll
            for (int i = 0; i < 4; i++) {
                int o = o0 + i;
                out[base + (size_t)o * HW] =
                    acc[tI][gidx * 4 + i] + b_out[o] + xin[base + (size_t)o * HW];
            }
        }
    }
}

// ---------------------------------------------------------------------------
// Launch. Workspace layout unchanged (off region unused). Weights ~1.5 MB
// fragment-major; wto1 OP=128; wt_in 16KB, wt_out 8KB.
// ---------------------------------------------------------------------------
extern "C" void kernel_launch(void* const* d_in, const int* in_sizes, int n_in,
                              void* d_out, int out_size, void* d_ws, size_t ws_size,
                              hipStream_t stream)
{
    const float* x     = (const float*)d_in[0];
    const float* ln_w  = (const float*)d_in[1];
    const float* ln_b  = (const float*)d_in[2];
    const float* w_in  = (const float*)d_in[3];
    const float* b_in  = (const float*)d_in[4];
    const float* w_out = (const float*)d_in[5];
    const float* b_out = (const float*)d_in[6];
    const float* dw1   = (const float*)d_in[7];
    const float* db1   = (const float*)d_in[8];
    const float* dw2   = (const float*)d_in[9];
    const float* db2   = (const float*)d_in[10];
    const float* dw3   = (const float*)d_in[11];
    const float* db3   = (const float*)d_in[12];
    const float* ow1   = (const float*)d_in[13];
    const float* ob1   = (const float*)d_in[14];
    const float* ow2   = (const float*)d_in[15];
    const float* ob2   = (const float*)d_in[16];
    const float* ow3   = (const float*)d_in[17];
    const float* ob3   = (const float*)d_in[18];

    _Float16* x1a = (_Float16*)d_ws;
    _Float16* x1b = x1a + (size_t)NPOS * 64;
    _Float16* x2  = x1b + (size_t)NPOS * 64;
    float* off = (float*)(x2 + (size_t)NPOS * 64);       // unused (kept for layout)
    _Float16* wtd1 = (_Float16*)(off + (size_t)NPOS * 100);
    _Float16* wtd2 = wtd1 + 49 * 64 * 64;
    _Float16* wtd3 = wtd2 + 25 * 64 * 64;
    _Float16* wto1 = wtd3 +  9 * 64 * 64;
    _Float16* wto2 = wto1 + 25 * 128 * 64;   // OP=128
    _Float16* wto3 = wto2 + 25 * 64 * 64;
    _Float16* wtin = wto3 +  9 * 32 * 64;
    _Float16* wtou = wtin + 128 * 64;

    // weight prep (fp16, fragment-major [tap][cs][o][8ch]); 1x1 convs KK=1
    k_wth<49, 64,  64><<<784, 256, 0, stream>>>(dw1, wtd1);
    k_wth<25, 64,  64><<<400, 256, 0, stream>>>(dw2, wtd2);
    k_wth< 9, 64,  64><<<144, 256, 0, stream>>>(dw3, wtd3);
    k_wth<25, 98, 128><<<800, 256, 0, stream>>>(ow1, wto1);
    k_wth<25, 50,  64><<<400, 256, 0, stream>>>(ow2, wto2);
    k_wth< 9, 18,  32><<< 72, 256, 0, stream>>>(ow3, wto3);
    k_wth< 1, 128, 128><<<32, 256, 0, stream>>>(w_in, wtin);
    k_wth< 1, 64,  64><<<16, 256, 0, stream>>>(w_out, wtou);

    // LN + 1x1 conv (MFMA)
    k_lnconv_mfma<<<NPOS / 128, 256, 0, stream>>>(x, ln_w, ln_b, wtin, b_in, x1a, x2);

    // fused offset+deform per stage (KD,PAD,HALO, KO,PADO, CT), 512 threads
    k_fconv<7, 3, 4, 5, 2, 4><<<1152, 512, 0, stream>>>(x1a, wto1, ob1, wtd1, db1, x1b);
    k_fconv<5, 2, 3, 5, 2, 2><<<1152, 512, 0, stream>>>(x1b, wto2, ob2, wtd2, db2, x1a);
    k_fconv<3, 1, 2, 3, 1, 1><<<1152, 512, 0, stream>>>(x1a, wto3, ob3, wtd3, db3, x1b);

    // merge + 1x1 conv + residual (MFMA)
    k_merge_mfma<<<NPOS / 128, 256, 0, stream>>>(x1b, x2, x, wtou, b_out, (float*)d_out);
}